// Round 1
// baseline (8060.049 us; speedup 1.0000x reference)
//
#include <hip/hip_runtime.h>
#include <hip/hip_bf16.h>

typedef __attribute__((ext_vector_type(8))) short bf16x8;
typedef __attribute__((ext_vector_type(4))) float f32x4;
typedef unsigned int u32;

// ---------------- helpers ----------------
__device__ __forceinline__ u32 bf16_1(float x) {
    u32 u = __float_as_uint(x);
    return (u + 0x7fffu + ((u >> 16) & 1u)) >> 16;   // RNE to bf16
}
__device__ __forceinline__ u32 packbf(float a, float b) {
    return bf16_1(a) | (bf16_1(b) << 16);
}

// ---------------- GEMM: C[M,N] = alpha * A[M,K] @ op(B) (+ Add) ----------------
// fp32 inputs converted to bf16 during LDS staging; fp32 MFMA accumulate.
// TRANSB=false: B is [K,N] row-major (ldb). TRANSB=true: B given as [N,K] row-major (ldb).
// grid = (M/128, N/128, Z); zA/zB/zC are per-z element strides (Add uses zC).
#define BM 128
#define BN 128
#define BKK 64
#define LDW 36   // uint words per LDS row = BKK/2 + 4 pad (2-way-max read conflicts)

template<bool TRANSB, bool ADD>
__global__ __launch_bounds__(256) void gemm_kernel(
    const float* __restrict__ A, int lda, long zA,
    const float* __restrict__ B, int ldb, long zB,
    float* __restrict__ C, int ldc, long zC,
    const float* __restrict__ Add,
    int K, float alpha)
{
    __shared__ __align__(16) u32 As[BM * LDW];
    __shared__ __align__(16) u32 Bs[BN * LDW];
    const int z = blockIdx.z;
    A += (long)z * zA;
    B += (long)z * zB;
    C += (long)z * zC;
    const float* Ad = ADD ? (Add + (long)z * zC) : nullptr;

    const int m0 = blockIdx.x * BM, n0 = blockIdx.y * BN;
    const int tid = threadIdx.x;
    const int lane = tid & 63, wave = tid >> 6;
    const int wm = wave & 1, wn = wave >> 1;       // 2x2 wave grid, each 64x64 out
    const int rl = lane & 15, gg = lane >> 4;      // frag row/col = rl, k-group = gg

    // staging index precompute
    const int a_kw = tid & 31, a_r0 = tid >> 5;    // A (and B-NT): word col, row base
    const int b_n = tid & 127, b_k0 = tid >> 7;    // B-NN transpose staging

    f32x4 zero4 = {0.f, 0.f, 0.f, 0.f};
    f32x4 acc[4][4];
#pragma unroll
    for (int i = 0; i < 4; ++i)
#pragma unroll
        for (int j = 0; j < 4; ++j) acc[i][j] = zero4;

    for (int k0 = 0; k0 < K; k0 += BKK) {
        // ---- stage A tile [128][64] as bf16 rows (k-contiguous) ----
#pragma unroll
        for (int it = 0; it < 16; ++it) {
            int r = a_r0 + it * 8;
            float2 v = *reinterpret_cast<const float2*>(A + (long)(m0 + r) * lda + k0 + 2 * a_kw);
            As[r * LDW + a_kw] = packbf(v.x, v.y);
        }
        // ---- stage B tile as rows of k (transpose in LDS when needed) ----
        if (TRANSB) {
#pragma unroll
            for (int it = 0; it < 16; ++it) {
                int r = a_r0 + it * 8;
                float2 v = *reinterpret_cast<const float2*>(B + (long)(n0 + r) * ldb + k0 + 2 * a_kw);
                Bs[r * LDW + a_kw] = packbf(v.x, v.y);
            }
        } else {
#pragma unroll
            for (int it = 0; it < 8; ++it) {
                int kq = b_k0 + it * 2;  // 0..15 quad of k
                const float* bp = B + (long)(k0 + 4 * kq) * ldb + n0 + b_n;
                float x0 = bp[0];
                float x1 = bp[ldb];
                float x2 = bp[2 * (long)ldb];
                float x3 = bp[3 * (long)ldb];
                uint2 w;
                w.x = packbf(x0, x1);
                w.y = packbf(x2, x3);
                *reinterpret_cast<uint2*>(&Bs[b_n * LDW + 2 * kq]) = w;
            }
        }
        __syncthreads();
        // ---- fragments + MFMA. k-slot map: slot(g,i) -> k = 32*kk + 8*g + i,
        //      identical for A and B, so result is invariant to HW k-order. ----
#pragma unroll
        for (int kk = 0; kk < 2; ++kk) {
            bf16x8 af[4], bq[4];
#pragma unroll
            for (int mf = 0; mf < 4; ++mf)
                af[mf] = *reinterpret_cast<const bf16x8*>(&As[(wm * 64 + mf * 16 + rl) * LDW + kk * 16 + gg * 4]);
#pragma unroll
            for (int nf = 0; nf < 4; ++nf)
                bq[nf] = *reinterpret_cast<const bf16x8*>(&Bs[(wn * 64 + nf * 16 + rl) * LDW + kk * 16 + gg * 4]);
#pragma unroll
            for (int mf = 0; mf < 4; ++mf)
#pragma unroll
                for (int nf = 0; nf < 4; ++nf)
                    acc[mf][nf] = __builtin_amdgcn_mfma_f32_16x16x32_bf16(af[mf], bq[nf], acc[mf][nf], 0, 0, 0);
        }
        __syncthreads();
    }
    // ---- epilogue: C/D layout col=lane&15, row=(lane>>4)*4+reg (HW-verified) ----
#pragma unroll
    for (int mf = 0; mf < 4; ++mf) {
#pragma unroll
        for (int nf = 0; nf < 4; ++nf) {
            int col = n0 + wn * 64 + nf * 16 + rl;
#pragma unroll
            for (int r = 0; r < 4; ++r) {
                int row = m0 + wm * 64 + mf * 16 + gg * 4 + r;
                long idx = (long)row * ldc + col;
                float v = acc[mf][nf][r] * alpha;
                if (ADD) v += Ad[idx];
                C[idx] = v;
            }
        }
    }
}

// ---------------- embedding gather ----------------
__global__ void embed_kernel(const int* __restrict__ ids, const float* __restrict__ emb,
                             float* __restrict__ x) {
    int idx = blockIdx.x * 256 + threadIdx.x;  // 1024*512 float4s
    int s = idx >> 9, c = idx & 511;
    float4 v = *reinterpret_cast<const float4*>(emb + (long)ids[s] * 2048 + c * 4);
    *reinterpret_cast<float4*>(x + (long)s * 2048 + c * 4) = v;
}

// ---------------- RMSNorm (row of 2048) ----------------
__global__ void rmsnorm_kernel(const float* __restrict__ x, const float* __restrict__ w,
                               float* __restrict__ o) {
    int row = blockIdx.x, t = threadIdx.x;
    const float* xr = x + (long)row * 2048;
    float4 v0 = *reinterpret_cast<const float4*>(xr + t * 4);
    float4 v1 = *reinterpret_cast<const float4*>(xr + 1024 + t * 4);
    float ss = v0.x * v0.x + v0.y * v0.y + v0.z * v0.z + v0.w * v0.w
             + v1.x * v1.x + v1.y * v1.y + v1.z * v1.z + v1.w * v1.w;
#pragma unroll
    for (int ofs = 32; ofs; ofs >>= 1) ss += __shfl_xor(ss, ofs);
    __shared__ float red[4];
    if ((t & 63) == 0) red[t >> 6] = ss;
    __syncthreads();
    ss = red[0] + red[1] + red[2] + red[3];
    float inv = 1.0f / sqrtf(ss * (1.0f / 2048.0f) + 1e-5f);
    float4 w0 = *reinterpret_cast<const float4*>(w + t * 4);
    float4 w1 = *reinterpret_cast<const float4*>(w + 1024 + t * 4);
    float* orow = o + (long)row * 2048;
    float4 o0, o1;
    o0.x = v0.x * inv * w0.x; o0.y = v0.y * inv * w0.y; o0.z = v0.z * inv * w0.z; o0.w = v0.w * inv * w0.w;
    o1.x = v1.x * inv * w1.x; o1.y = v1.y * inv * w1.y; o1.z = v1.z * inv * w1.z; o1.w = v1.w * inv * w1.w;
    *reinterpret_cast<float4*>(orow + t * 4) = o0;
    *reinterpret_cast<float4*>(orow + 1024 + t * 4) = o1;
}

// ---------------- RoPE on q in place (pos = 2048+s) ----------------
__global__ void rope_q_kernel(float* __restrict__ q) {
    int idx = blockIdx.x * 256 + threadIdx.x;  // 1024*16*64
    int fi = idx & 63;
    int hh = (idx >> 6) & 15;
    int s = idx >> 10;
    float* p = q + (long)s * 2048 + hh * 128 + fi;
    float q0 = p[0], q1 = p[64];
    float inv = exp2f((float)fi * -0.20762050593046014f);  // 10000^(-fi/64)
    float ang = (float)(2048 + s) * inv;
    float sn, cs;
    sincosf(ang, &sn, &cs);
    p[0] = q0 * cs - q1 * sn;
    p[64] = q1 * cs + q0 * sn;
}

// ---------------- build K/V [16][3072][128]: cache + repeated new, RoPE on K ----------------
__global__ void build_kv_kernel(const float* __restrict__ kc, const float* __restrict__ vc,
                                const float* __restrict__ kn, const float* __restrict__ vn,
                                float* __restrict__ kf, float* __restrict__ vf) {
    int t = blockIdx.x * 256 + threadIdx.x;  // 3072*64 per head
    int hh = blockIdx.y;
    int fi = t & 63;
    int j = t >> 6;  // 0..3071
    float k0, k1, v0, v1;
    if (j < 2048) {
        const float* kp = kc + ((long)hh * 2048 + j) * 128;
        const float* vp = vc + ((long)hh * 2048 + j) * 128;
        k0 = kp[fi]; k1 = kp[fi + 64];
        v0 = vp[fi]; v1 = vp[fi + 64];
    } else {
        int s = j - 2048;
        const float* kp = kn + (long)s * 512 + (hh >> 2) * 128;
        const float* vp = vn + (long)s * 512 + (hh >> 2) * 128;
        k0 = kp[fi]; k1 = kp[fi + 64];
        v0 = vp[fi]; v1 = vp[fi + 64];
    }
    float inv = exp2f((float)fi * -0.20762050593046014f);
    float ang = (float)j * inv;
    float sn, cs;
    sincosf(ang, &sn, &cs);
    float* kd = kf + ((long)hh * 3072 + j) * 128;
    float* vd = vf + ((long)hh * 3072 + j) * 128;
    kd[fi] = k0 * cs - k1 * sn;
    kd[fi + 64] = k1 * cs + k0 * sn;
    vd[fi] = v0;
    vd[fi + 64] = v1;
}

// ---------------- mask + softmax over rows of 3072 (in place) ----------------
__global__ void softmax_kernel(float* __restrict__ sc, int qb) {
    int i = blockIdx.x, hh = blockIdx.y, t = threadIdx.x;
    float* row = sc + ((long)hh * 512 + i) * 3072;
    int qg = qb * 512 + i;  // global q index 0..1023
    float vals[12];
    float mx = -1e30f;
#pragma unroll
    for (int it = 0; it < 12; ++it) {
        int j = t + it * 256;
        float s = row[j];
        int jj = j - 2048;
        bool vis = (j < 2048) || (((jj >> 9) == (qg >> 9)) && (jj <= qg));
        s = vis ? s : -INFINITY;
        vals[it] = s;
        mx = fmaxf(mx, s);
    }
#pragma unroll
    for (int ofs = 32; ofs; ofs >>= 1) mx = fmaxf(mx, __shfl_xor(mx, ofs));
    __shared__ float red[4];
    if ((t & 63) == 0) red[t >> 6] = mx;
    __syncthreads();
    mx = fmaxf(fmaxf(red[0], red[1]), fmaxf(red[2], red[3]));
    float sum = 0.f;
#pragma unroll
    for (int it = 0; it < 12; ++it) {
        float e = __expf(vals[it] - mx);
        vals[it] = e;
        sum += e;
    }
#pragma unroll
    for (int ofs = 32; ofs; ofs >>= 1) sum += __shfl_xor(sum, ofs);
    __syncthreads();
    if ((t & 63) == 0) red[t >> 6] = sum;
    __syncthreads();
    sum = red[0] + red[1] + red[2] + red[3];
    float inv = 1.0f / sum;
#pragma unroll
    for (int it = 0; it < 12; ++it) row[t + it * 256] = vals[it] * inv;
}

// ---------------- SiLU(g) * u, in place into g ----------------
__global__ void silu_mul_kernel(float* __restrict__ g, const float* __restrict__ u) {
    long idx = (long)blockIdx.x * 256 + threadIdx.x;
    float gv = g[idx], uv = u[idx];
    g[idx] = (gv / (1.0f + __expf(-gv))) * uv;
}

// ---------------- host ----------------
extern "C" void kernel_launch(void* const* d_in, const int* in_sizes, int n_in,
                              void* d_out, int out_size, void* d_ws, size_t ws_size,
                              hipStream_t stream) {
    const int*   ids   = (const int*)d_in[0];
    const float* kv    = (const float*)d_in[1];
    const float* emb   = (const float*)d_in[2];
    const float* Wq    = (const float*)d_in[3];
    const float* Wk    = (const float*)d_in[4];
    const float* Wv    = (const float*)d_in[5];
    const float* Wo    = (const float*)d_in[6];
    const float* ln1   = (const float*)d_in[7];
    const float* ln2   = (const float*)d_in[8];
    const float* Wg    = (const float*)d_in[9];
    const float* Wu    = (const float*)d_in[10];
    const float* Wd    = (const float*)d_in[11];
    const float* normw = (const float*)d_in[12];
    const float* lmh   = (const float*)d_in[13];
    float* out = (float*)d_out;

    float* ws   = (float*)d_ws;
    float* x    = ws;                  // [1024,2048]
    float* h    = x    + 2097152;      // [1024,2048]
    float* q    = h    + 2097152;      // [1024,2048]
    float* kn   = q    + 2097152;      // [1024,512]
    float* vn   = kn   + 524288;       // [1024,512]
    float* kf   = vn   + 524288;       // [16,3072,128]
    float* vf   = kf   + 6291456;      // [16,3072,128]
    float* sc   = vf   + 6291456;      // [16,512,3072] (per q-chunk)
    float* attn = sc   + 25165824;     // [1024,2048]
    float* gbuf = attn + 2097152;      // [1024,5632]
    float* ubuf = gbuf + 5767168;      // [1024,5632]
    (void)ws_size; (void)in_sizes; (void)n_in; (void)out_size;

    embed_kernel<<<2048, 256, 0, stream>>>(ids, emb, x);

    for (int l = 0; l < 2; ++l) {
        const float* Wq_l = Wq + (long)l * 2048 * 2048;
        const float* Wk_l = Wk + (long)l * 2048 * 512;
        const float* Wv_l = Wv + (long)l * 2048 * 512;
        const float* Wo_l = Wo + (long)l * 2048 * 2048;
        const float* Wg_l = Wg + (long)l * 2048 * 5632;
        const float* Wu_l = Wu + (long)l * 2048 * 5632;
        const float* Wd_l = Wd + (long)l * 5632 * 2048;
        const float* kc = kv + (long)l * 16 * 2048 * 128;        // kv_caches[0][l]
        const float* vc = kv + (long)(2 + l) * 16 * 2048 * 128;  // kv_caches[1][l]

        rmsnorm_kernel<<<1024, 256, 0, stream>>>(x, ln1 + l * 2048, h);
        gemm_kernel<false, false><<<dim3(8, 16, 1), 256, 0, stream>>>(
            h, 2048, 0, Wq_l, 2048, 0, q, 2048, 0, nullptr, 2048, 1.0f);
        gemm_kernel<false, false><<<dim3(8, 4, 1), 256, 0, stream>>>(
            h, 2048, 0, Wk_l, 512, 0, kn, 512, 0, nullptr, 2048, 1.0f);
        gemm_kernel<false, false><<<dim3(8, 4, 1), 256, 0, stream>>>(
            h, 2048, 0, Wv_l, 512, 0, vn, 512, 0, nullptr, 2048, 1.0f);
        rope_q_kernel<<<4096, 256, 0, stream>>>(q);
        build_kv_kernel<<<dim3(768, 16), 256, 0, stream>>>(kc, vc, kn, vn, kf, vf);

        for (int qb = 0; qb < 2; ++qb) {
            // scores[h][i][j] = scale * q_h[qb*512+i] . kf_h[j]   (NT GEMM)
            gemm_kernel<true, false><<<dim3(4, 24, 16), 256, 0, stream>>>(
                q + (long)qb * 512 * 2048, 2048, 128,
                kf, 128, (long)3072 * 128,
                sc, 3072, (long)512 * 3072, nullptr, 128, 0.08838834764831845f);
            softmax_kernel<<<dim3(512, 16), 256, 0, stream>>>(sc, qb);
            // attn[qb*512+i][h*128+d] = probs @ v_h   (NN GEMM)
            gemm_kernel<false, false><<<dim3(4, 1, 16), 256, 0, stream>>>(
                sc, 3072, (long)512 * 3072,
                vf, 128, (long)3072 * 128,
                attn + (long)qb * 512 * 2048, 2048, 128, nullptr, 3072, 1.0f);
        }

        gemm_kernel<false, true><<<dim3(8, 16, 1), 256, 0, stream>>>(
            attn, 2048, 0, Wo_l, 2048, 0, x, 2048, 0, x, 2048, 1.0f);
        rmsnorm_kernel<<<1024, 256, 0, stream>>>(x, ln2 + l * 2048, h);
        gemm_kernel<false, false><<<dim3(8, 44, 1), 256, 0, stream>>>(
            h, 2048, 0, Wg_l, 5632, 0, gbuf, 5632, 0, nullptr, 2048, 1.0f);
        gemm_kernel<false, false><<<dim3(8, 44, 1), 256, 0, stream>>>(
            h, 2048, 0, Wu_l, 5632, 0, ubuf, 5632, 0, nullptr, 2048, 1.0f);
        silu_mul_kernel<<<22528, 256, 0, stream>>>(gbuf, ubuf);
        gemm_kernel<false, true><<<dim3(8, 16, 1), 256, 0, stream>>>(
            gbuf, 5632, 0, Wd_l, 2048, 0, x, 2048, 0, x, 5632, 1.0f);
    }

    rmsnorm_kernel<<<1024, 256, 0, stream>>>(x, normw, h);
    gemm_kernel<false, false><<<dim3(8, 250, 1), 256, 0, stream>>>(
        h, 2048, 0, lmh, 32000, 0, out, 32000, 0, nullptr, 2048, 1.0f);
}

// Round 2
// 1831.325 us; speedup vs baseline: 4.4012x; 4.4012x over previous
//
#include <hip/hip_runtime.h>
#include <hip/hip_bf16.h>
#include <stdint.h>

typedef __attribute__((ext_vector_type(8))) short bf16x8;
typedef __attribute__((ext_vector_type(4))) float f32x4;
typedef unsigned int u32;
typedef unsigned short u16;

// ---------------- helpers ----------------
__device__ __forceinline__ u32 bf16_1(float x) {
    u32 u = __float_as_uint(x);
    return (u + 0x7fffu + ((u >> 16) & 1u)) >> 16;   // RNE to bf16
}
__device__ __forceinline__ u32 packbf(float a, float b) {
    return bf16_1(a) | (bf16_1(b) << 16);
}
__device__ __forceinline__ float bf2f(u16 v) {
    return __uint_as_float(((u32)v) << 16);
}

typedef const __attribute__((address_space(1))) u32* gptr_t;
typedef __attribute__((address_space(3))) u32* lptr_t;
__device__ __forceinline__ void gload16(const u16* g, u16* l) {
    // async global->LDS, 16B per lane; LDS dest is wave-uniform base + lane*16
    __builtin_amdgcn_global_load_lds((gptr_t)g, (lptr_t)l, 16, 0, 0);
}

// ============ bf16 GEMM: C[M,N] = alpha * A[M,K] @ B^T[N,K] (+ Add) ============
// m97-class: 128x128 tile, BK=64, global_load_lds staging, XOR-swizzled LDS.
// Swizzle (rule 21, both-sides): LDS slot s of row r holds source chunk s^(r&7);
// ds_read of chunk c uses slot c^(r&7). 2-way conflicts only (free).
template<typename OUT, bool ADD>
__global__ __launch_bounds__(256) void bgemm_kernel(
    const u16* __restrict__ A, int lda, long zA,
    const u16* __restrict__ B, int ldb, long zB,
    OUT* __restrict__ C, int ldc, long zC,
    const float* __restrict__ Add,
    int K, float alpha)
{
    __shared__ __align__(16) u16 As[128 * 64];
    __shared__ __align__(16) u16 Bs[128 * 64];
    const int z = blockIdx.z;
    A += (long)z * zA;
    B += (long)z * zB;
    C += (long)z * zC;
    const float* Ad = ADD ? (Add + (long)z * zC) : nullptr;

    const int m0 = blockIdx.x * 128, n0 = blockIdx.y * 128;
    const int tid = threadIdx.x;
    const int lane = tid & 63, wave = tid >> 6;
    const int wm = wave & 1, wn = wave >> 1;
    const int rl = lane & 15, gg = lane >> 4;
    const int srow = lane >> 3, schunk = lane & 7;

    f32x4 zero4 = {0.f, 0.f, 0.f, 0.f};
    f32x4 acc[4][4];
#pragma unroll
    for (int i = 0; i < 4; ++i)
#pragma unroll
        for (int j = 0; j < 4; ++j) acc[i][j] = zero4;

    for (int k0 = 0; k0 < K; k0 += 64) {
#pragma unroll
        for (int it = 0; it < 4; ++it) {
            int ii = wave * 4 + it;          // 16 instrs cover 128 rows (8 rows each)
            int row = ii * 8 + srow;
            int sc_ = (schunk ^ (row & 7)) << 3;   // inverse-swizzled source chunk
            gload16(A + (long)(m0 + row) * lda + k0 + sc_, &As[ii * 512]);
            gload16(B + (long)(n0 + row) * ldb + k0 + sc_, &Bs[ii * 512]);
        }
        __syncthreads();
#pragma unroll
        for (int kk = 0; kk < 2; ++kk) {
            bf16x8 af[4], bq[4];
#pragma unroll
            for (int mf = 0; mf < 4; ++mf) {
                int row = wm * 64 + mf * 16 + rl;
                af[mf] = *reinterpret_cast<const bf16x8*>(&As[row * 64 + (((kk * 4 + gg) ^ (row & 7)) << 3)]);
            }
#pragma unroll
            for (int nf = 0; nf < 4; ++nf) {
                int row = wn * 64 + nf * 16 + rl;
                bq[nf] = *reinterpret_cast<const bf16x8*>(&Bs[row * 64 + (((kk * 4 + gg) ^ (row & 7)) << 3)]);
            }
#pragma unroll
            for (int mf = 0; mf < 4; ++mf)
#pragma unroll
                for (int nf = 0; nf < 4; ++nf)
                    acc[mf][nf] = __builtin_amdgcn_mfma_f32_16x16x32_bf16(af[mf], bq[nf], acc[mf][nf], 0, 0, 0);
        }
        __syncthreads();
    }
    // epilogue: C/D layout col=lane&15, row=(lane>>4)*4+reg (HW-verified, r1 passed)
#pragma unroll
    for (int mf = 0; mf < 4; ++mf) {
#pragma unroll
        for (int nf = 0; nf < 4; ++nf) {
            int col = n0 + wn * 64 + nf * 16 + rl;
#pragma unroll
            for (int r = 0; r < 4; ++r) {
                int row = m0 + wm * 64 + mf * 16 + gg * 4 + r;
                long idx = (long)row * ldc + col;
                float v = acc[mf][nf][r] * alpha;
                if (ADD) v += Ad[idx];
                if constexpr (sizeof(OUT) == 2) ((u16*)C)[idx] = (u16)bf16_1(v);
                else C[idx] = v;
            }
        }
    }
}

// ============ transpose-convert: W[K,N] fp32 -> WT[N,K] bf16 ============
// grid.x = col-tiles (64) starting at n0, grid.y = K/64
__global__ void convT_kernel(const float* __restrict__ W, int ldw, int n0,
                             u16* __restrict__ WT, int ldk) {
    __shared__ float tile[64][65];
    int t = threadIdx.x;
    int c = t & 63, r4 = t >> 6;
    const float* src = W + (long)(blockIdx.y * 64 + r4) * ldw + n0 + blockIdx.x * 64 + c;
#pragma unroll
    for (int p = 0; p < 16; ++p)
        tile[r4 + p * 4][c] = src[(long)p * 4 * ldw];
    __syncthreads();
    int kp = t & 31, cc = t >> 5;
#pragma unroll
    for (int p = 0; p < 8; ++p) {
        int crow = cc + p * 8;
        float a = tile[kp * 2][crow], b = tile[kp * 2 + 1][crow];
        ((u32*)WT)[(((long)(blockIdx.x * 64 + crow) * ldk + blockIdx.y * 64) >> 1) + kp] = packbf(a, b);
    }
}

// ---------------- embedding gather (fp32 residual stream) ----------------
__global__ void embed_kernel(const int* __restrict__ ids, const float* __restrict__ emb,
                             float* __restrict__ x) {
    int idx = blockIdx.x * 256 + threadIdx.x;
    int s = idx >> 9, c = idx & 511;
    float4 v = *reinterpret_cast<const float4*>(emb + (long)ids[s] * 2048 + c * 4);
    *reinterpret_cast<float4*>(x + (long)s * 2048 + c * 4) = v;
}

// ---------------- RMSNorm: fp32 in -> bf16 out ----------------
__global__ void rmsnorm_kernel(const float* __restrict__ x, const float* __restrict__ w,
                               u16* __restrict__ o) {
    int row = blockIdx.x, t = threadIdx.x;
    const float* xr = x + (long)row * 2048;
    float4 v0 = *reinterpret_cast<const float4*>(xr + t * 4);
    float4 v1 = *reinterpret_cast<const float4*>(xr + 1024 + t * 4);
    float ss = v0.x * v0.x + v0.y * v0.y + v0.z * v0.z + v0.w * v0.w
             + v1.x * v1.x + v1.y * v1.y + v1.z * v1.z + v1.w * v1.w;
#pragma unroll
    for (int ofs = 32; ofs; ofs >>= 1) ss += __shfl_xor(ss, ofs);
    __shared__ float red[4];
    if ((t & 63) == 0) red[t >> 6] = ss;
    __syncthreads();
    ss = red[0] + red[1] + red[2] + red[3];
    float inv = 1.0f / sqrtf(ss * (1.0f / 2048.0f) + 1e-5f);
    float4 w0 = *reinterpret_cast<const float4*>(w + t * 4);
    float4 w1 = *reinterpret_cast<const float4*>(w + 1024 + t * 4);
    u32* op = (u32*)(o + (long)row * 2048);
    op[t * 2]       = packbf(v0.x * inv * w0.x, v0.y * inv * w0.y);
    op[t * 2 + 1]   = packbf(v0.z * inv * w0.z, v0.w * inv * w0.w);
    op[512 + t * 2]     = packbf(v1.x * inv * w1.x, v1.y * inv * w1.y);
    op[512 + t * 2 + 1] = packbf(v1.z * inv * w1.z, v1.w * inv * w1.w);
}

// ---------------- RoPE on q (bf16, in place, pos = 2048+s) ----------------
__global__ void rope_q_kernel(u16* __restrict__ q) {
    int idx = blockIdx.x * 256 + threadIdx.x;  // 1024*16*64
    int fi = idx & 63;
    int hh = (idx >> 6) & 15;
    int s = idx >> 10;
    u16* p = q + (long)s * 2048 + hh * 128 + fi;
    float q0 = bf2f(p[0]), q1 = bf2f(p[64]);
    float inv = exp2f((float)fi * -0.20762050593046014f);  // 10000^(-fi/64)
    float ang = (float)(2048 + s) * inv;
    float sn, cs;
    sincosf(ang, &sn, &cs);
    p[0]  = (u16)bf16_1(q0 * cs - q1 * sn);
    p[64] = (u16)bf16_1(q1 * cs + q0 * sn);
}

// ---------------- build K [16][3072][128] bf16 (cache + repeated new, RoPE) ----------------
__global__ void build_k_kernel(const float* __restrict__ kc, const u16* __restrict__ kn,
                               u16* __restrict__ kf) {
    int t = blockIdx.x * 256 + threadIdx.x;  // 3072*64 per head
    int hh = blockIdx.y;
    int fi = t & 63;
    int j = t >> 6;
    float k0, k1;
    if (j < 2048) {
        const float* kp = kc + ((long)hh * 2048 + j) * 128;
        k0 = kp[fi]; k1 = kp[fi + 64];
    } else {
        int s = j - 2048;
        const u16* kp = kn + (long)s * 512 + (hh >> 2) * 128;
        k0 = bf2f(kp[fi]); k1 = bf2f(kp[fi + 64]);
    }
    float inv = exp2f((float)fi * -0.20762050593046014f);
    float ang = (float)j * inv;
    float sn, cs;
    sincosf(ang, &sn, &cs);
    u16* kd = kf + ((long)hh * 3072 + j) * 128;
    kd[fi]      = (u16)bf16_1(k0 * cs - k1 * sn);
    kd[fi + 64] = (u16)bf16_1(k1 * cs + k0 * sn);
}

// ---------------- build V^T [16][128][3072] bf16 via LDS transpose ----------------
__global__ void build_vT_kernel(const float* __restrict__ vc, const u16* __restrict__ vn,
                                u16* __restrict__ vfT) {
    __shared__ u16 tile[64][137];
    int hh = blockIdx.y, j0 = blockIdx.x * 64;
    int t = threadIdx.x;
    int d = t & 127, jr = t >> 7;
#pragma unroll
    for (int p = 0; p < 32; ++p) {
        int j = jr + p * 2;
        int gj = j0 + j;
        float v;
        if (gj < 2048) v = vc[((long)hh * 2048 + gj) * 128 + d];
        else           v = bf2f(vn[(long)(gj - 2048) * 512 + (hh >> 2) * 128 + d]);
        tile[j][d] = (u16)bf16_1(v);
    }
    __syncthreads();
    int jp = t & 31, dd = t >> 5;
#pragma unroll
    for (int p = 0; p < 16; ++p) {
        int d2 = dd + p * 8;
        u32 w = (u32)tile[jp * 2][d2] | ((u32)tile[jp * 2 + 1][d2] << 16);
        ((u32*)vfT)[((long)hh * 128 + d2) * 1536 + (j0 >> 1) + jp] = w;
    }
}

// ---------------- mask + softmax: sc fp32 [16][128][3072] -> probs bf16 chunk ----------------
__global__ void softmax_kernel(const float* __restrict__ sc, u16* __restrict__ probs,
                               int qg0, int sub) {
    int i = blockIdx.x, hh = blockIdx.y, t = threadIdx.x;
    const float* row = sc + ((long)hh * 128 + i) * 3072;
    u16* prow = probs + ((long)hh * 512 + sub * 128 + i) * 3072;
    int qg = qg0 + i;
    float vals[12];
    float mx = -1e30f;
#pragma unroll
    for (int it = 0; it < 12; ++it) {
        int j = t + it * 256;
        float s = row[j];
        int jj = j - 2048;
        bool vis = (j < 2048) || (((jj >> 9) == (qg >> 9)) && (jj <= qg));
        s = vis ? s : -INFINITY;
        vals[it] = s;
        mx = fmaxf(mx, s);
    }
#pragma unroll
    for (int ofs = 32; ofs; ofs >>= 1) mx = fmaxf(mx, __shfl_xor(mx, ofs));
    __shared__ float red[4];
    if ((t & 63) == 0) red[t >> 6] = mx;
    __syncthreads();
    mx = fmaxf(fmaxf(red[0], red[1]), fmaxf(red[2], red[3]));
    float sum = 0.f;
#pragma unroll
    for (int it = 0; it < 12; ++it) {
        float e = __expf(vals[it] - mx);
        vals[it] = e;
        sum += e;
    }
#pragma unroll
    for (int ofs = 32; ofs; ofs >>= 1) sum += __shfl_xor(sum, ofs);
    __syncthreads();
    if ((t & 63) == 0) red[t >> 6] = sum;
    __syncthreads();
    sum = red[0] + red[1] + red[2] + red[3];
    float inv = 1.0f / sum;
#pragma unroll
    for (int it = 0; it < 12; ++it) prow[t + it * 256] = (u16)bf16_1(vals[it] * inv);
}

// ---------------- SiLU(g)*u, bf16 x2 packed, in place into g ----------------
__global__ void silu_mul_kernel(u32* __restrict__ g, const u32* __restrict__ u) {
    long idx = (long)blockIdx.x * 256 + threadIdx.x;
    u32 gv = g[idx], uv = u[idx];
    float g0 = bf2f((u16)(gv & 0xffff)), g1 = bf2f((u16)(gv >> 16));
    float u0 = bf2f((u16)(uv & 0xffff)), u1 = bf2f((u16)(uv >> 16));
    float r0 = (g0 / (1.0f + __expf(-g0))) * u0;
    float r1 = (g1 / (1.0f + __expf(-g1))) * u1;
    g[idx] = packbf(r0, r1);
}

// ---------------- host ----------------
extern "C" void kernel_launch(void* const* d_in, const int* in_sizes, int n_in,
                              void* d_out, int out_size, void* d_ws, size_t ws_size,
                              hipStream_t stream) {
    const int*   ids   = (const int*)d_in[0];
    const float* kv    = (const float*)d_in[1];
    const float* emb   = (const float*)d_in[2];
    const float* Wq    = (const float*)d_in[3];
    const float* Wk    = (const float*)d_in[4];
    const float* Wv    = (const float*)d_in[5];
    const float* Wo    = (const float*)d_in[6];
    const float* ln1   = (const float*)d_in[7];
    const float* ln2   = (const float*)d_in[8];
    const float* Wg    = (const float*)d_in[9];
    const float* Wu    = (const float*)d_in[10];
    const float* Wd    = (const float*)d_in[11];
    const float* normw = (const float*)d_in[12];
    const float* lmh   = (const float*)d_in[13];
    float* out = (float*)d_out;
    (void)in_sizes; (void)n_in; (void)out_size; (void)ws_size;

    char* w = (char*)d_ws;
    u16*   wt      = (u16*)w;                        // layer weights bf16^T, 90,177,536 B (also lm chunks)
    float* x       = (float*)(w + 90177536);         // [1024,2048] fp32
    u16*   h       = (u16*)(w + 98566144);           // [1024,2048] bf16
    u16*   q       = (u16*)(w + 102760448);          // [1024,2048] bf16
    u16*   kf      = (u16*)(w + 106954752);          // [16,3072,128] bf16
    u16*   vfT     = (u16*)(w + 119537664);          // [16,128,3072] bf16
    char*  scratch = w + 132120576;                  // 25,165,824 B: {kn,vn} / sc / {g,u}
    u16*   probs   = (u16*)(w + 157286400);          // [16,512,3072] bf16 (per q-chunk)
    u16*   attn    = (u16*)(w + 207618048);          // [1024,2048] bf16
    u16*   kn = (u16*)scratch;
    u16*   vn = kn + 524288;
    float* sc = (float*)scratch;                     // [16,128,3072] fp32
    u16*   g  = (u16*)scratch;                       // [1024,5632] bf16
    u16*   u  = g + 5767168;                         // [1024,5632] bf16

    // wt sub-offsets (bf16 elements)
    u16* WqT = wt;                // [2048][2048]
    u16* WkT = wt + 4194304;      // [512][2048]
    u16* WvT = wt + 5242880;      // [512][2048]
    u16* WoT = wt + 6291456;      // [2048][2048]
    u16* WgT = wt + 10485760;     // [5632][2048]
    u16* WuT = wt + 22020096;     // [5632][2048]
    u16* WdT = wt + 33554432;     // [2048][5632]

    const float scale = 0.08838834764831845f;

    embed_kernel<<<2048, 256, 0, stream>>>(ids, emb, x);

    for (int l = 0; l < 2; ++l) {
        const float* Wq_l = Wq + (long)l * 2048 * 2048;
        const float* Wk_l = Wk + (long)l * 2048 * 512;
        const float* Wv_l = Wv + (long)l * 2048 * 512;
        const float* Wo_l = Wo + (long)l * 2048 * 2048;
        const float* Wg_l = Wg + (long)l * 2048 * 5632;
        const float* Wu_l = Wu + (long)l * 2048 * 5632;
        const float* Wd_l = Wd + (long)l * 5632 * 2048;
        const float* kc = kv + (long)l * 16 * 2048 * 128;        // kv_caches[0][l]
        const float* vc = kv + (long)(2 + l) * 16 * 2048 * 128;  // kv_caches[1][l]

        // weight conversion (fp32 [K,N] -> bf16 [N,K])
        convT_kernel<<<dim3(32, 32), 256, 0, stream>>>(Wq_l, 2048, 0, WqT, 2048);
        convT_kernel<<<dim3(8, 32),  256, 0, stream>>>(Wk_l, 512,  0, WkT, 2048);
        convT_kernel<<<dim3(8, 32),  256, 0, stream>>>(Wv_l, 512,  0, WvT, 2048);
        convT_kernel<<<dim3(32, 32), 256, 0, stream>>>(Wo_l, 2048, 0, WoT, 2048);
        convT_kernel<<<dim3(88, 32), 256, 0, stream>>>(Wg_l, 5632, 0, WgT, 2048);
        convT_kernel<<<dim3(88, 32), 256, 0, stream>>>(Wu_l, 5632, 0, WuT, 2048);
        convT_kernel<<<dim3(32, 88), 256, 0, stream>>>(Wd_l, 2048, 0, WdT, 5632);

        rmsnorm_kernel<<<1024, 256, 0, stream>>>(x, ln1 + l * 2048, h);
        bgemm_kernel<u16, false><<<dim3(8, 16, 1), 256, 0, stream>>>(
            h, 2048, 0, WqT, 2048, 0, q, 2048, 0, nullptr, 2048, 1.0f);
        bgemm_kernel<u16, false><<<dim3(8, 4, 1), 256, 0, stream>>>(
            h, 2048, 0, WkT, 2048, 0, kn, 512, 0, nullptr, 2048, 1.0f);
        bgemm_kernel<u16, false><<<dim3(8, 4, 1), 256, 0, stream>>>(
            h, 2048, 0, WvT, 2048, 0, vn, 512, 0, nullptr, 2048, 1.0f);
        rope_q_kernel<<<4096, 256, 0, stream>>>(q);
        build_k_kernel<<<dim3(768, 16), 256, 0, stream>>>(kc, kn, kf);
        build_vT_kernel<<<dim3(48, 16), 256, 0, stream>>>(vc, vn, vfT);

        for (int qb = 0; qb < 2; ++qb) {
            for (int sub = 0; sub < 4; ++sub) {
                int row0 = qb * 512 + sub * 128;
                bgemm_kernel<float, false><<<dim3(1, 24, 16), 256, 0, stream>>>(
                    q + (long)row0 * 2048, 2048, 128,
                    kf, 128, (long)3072 * 128,
                    sc, 3072, (long)128 * 3072, nullptr, 128, scale);
                softmax_kernel<<<dim3(128, 16), 256, 0, stream>>>(sc, probs, row0, sub);
            }
            bgemm_kernel<u16, false><<<dim3(4, 1, 16), 256, 0, stream>>>(
                probs, 3072, (long)512 * 3072,
                vfT, 3072, (long)128 * 3072,
                attn + (long)qb * 512 * 2048, 2048, 128, nullptr, 3072, 1.0f);
        }

        bgemm_kernel<float, true><<<dim3(8, 16, 1), 256, 0, stream>>>(
            attn, 2048, 0, WoT, 2048, 0, x, 2048, 0, x, 2048, 1.0f);
        rmsnorm_kernel<<<1024, 256, 0, stream>>>(x, ln2 + l * 2048, h);
        bgemm_kernel<u16, false><<<dim3(8, 44, 1), 256, 0, stream>>>(
            h, 2048, 0, WgT, 2048, 0, g, 5632, 0, nullptr, 2048, 1.0f);
        bgemm_kernel<u16, false><<<dim3(8, 44, 1), 256, 0, stream>>>(
            h, 2048, 0, WuT, 2048, 0, u, 5632, 0, nullptr, 2048, 1.0f);
        silu_mul_kernel<<<11264, 256, 0, stream>>>((u32*)g, (const u32*)u);
        bgemm_kernel<float, true><<<dim3(8, 16, 1), 256, 0, stream>>>(
            g, 5632, 0, WdT, 5632, 0, x, 2048, 0, x, 5632, 1.0f);
    }

    rmsnorm_kernel<<<1024, 256, 0, stream>>>(x, normw, h);
    // lm_head in 5 column chunks of 6400 (convert into wt region, then GEMM)
    for (int c = 0; c < 5; ++c) {
        int c0 = c * 6400;
        convT_kernel<<<dim3(100, 32), 256, 0, stream>>>(lmh, 32000, c0, wt, 2048);
        bgemm_kernel<float, false><<<dim3(8, 50, 1), 256, 0, stream>>>(
            h, 2048, 0, wt, 2048, 0, out + c0, 32000, 0, nullptr, 2048, 1.0f);
    }
}

// Round 3
// 1165.441 us; speedup vs baseline: 6.9159x; 1.5714x over previous
//
#include <hip/hip_runtime.h>
#include <hip/hip_bf16.h>
#include <stdint.h>

typedef __attribute__((ext_vector_type(8))) short bf16x8;
typedef __attribute__((ext_vector_type(4))) float f32x4;
typedef unsigned int u32;
typedef unsigned short u16;

// ---------------- helpers ----------------
__device__ __forceinline__ u32 bf16_1(float x) {
    u32 u = __float_as_uint(x);
    return (u + 0x7fffu + ((u >> 16) & 1u)) >> 16;   // RNE to bf16
}
__device__ __forceinline__ u32 packbf(float a, float b) {
    return bf16_1(a) | (bf16_1(b) << 16);
}
__device__ __forceinline__ float bf2f(u16 v) {
    return __uint_as_float(((u32)v) << 16);
}

typedef const __attribute__((address_space(1))) u32* gptr_t;
typedef __attribute__((address_space(3))) u32* lptr_t;
__device__ __forceinline__ void gload16(const u16* g, u16* l) {
    __builtin_amdgcn_global_load_lds((gptr_t)g, (lptr_t)l, 16, 0, 0);
}

// ============ bf16 GEMM: C[M,N] = alpha * A[M,K] @ B^T[N,K] (+ Add / mask) ============
// 128x128 tile, BK=64, global_load_lds staging, XOR-swizzled LDS (rule 21 both-sides).
// MASK: hybrid attention mask applied in epilogue (row = global q idx, col = kv idx),
//       masked elements -> -inf (bf16 0xFF80).
template<typename OUT, bool ADD, bool MASK>
__global__ __launch_bounds__(256) void bgemm_kernel(
    const u16* __restrict__ A, int lda, long zA,
    const u16* __restrict__ B, int ldb, long zB,
    OUT* __restrict__ C, int ldc, long zC,
    const float* __restrict__ Add,
    int K, float alpha)
{
    __shared__ __align__(16) u16 As[128 * 64];
    __shared__ __align__(16) u16 Bs[128 * 64];
    const int z = blockIdx.z;
    A += (long)z * zA;
    B += (long)z * zB;
    C += (long)z * zC;
    const float* Ad = ADD ? (Add + (long)z * zC) : nullptr;

    const int m0 = blockIdx.x * 128, n0 = blockIdx.y * 128;
    const int tid = threadIdx.x;
    const int lane = tid & 63, wave = tid >> 6;
    const int wm = wave & 1, wn = wave >> 1;
    const int rl = lane & 15, gg = lane >> 4;
    const int srow = lane >> 3, schunk = lane & 7;

    f32x4 zero4 = {0.f, 0.f, 0.f, 0.f};
    f32x4 acc[4][4];
#pragma unroll
    for (int i = 0; i < 4; ++i)
#pragma unroll
        for (int j = 0; j < 4; ++j) acc[i][j] = zero4;

    for (int k0 = 0; k0 < K; k0 += 64) {
#pragma unroll
        for (int it = 0; it < 4; ++it) {
            int ii = wave * 4 + it;
            int row = ii * 8 + srow;
            int sc_ = (schunk ^ (row & 7)) << 3;
            gload16(A + (long)(m0 + row) * lda + k0 + sc_, &As[ii * 512]);
            gload16(B + (long)(n0 + row) * ldb + k0 + sc_, &Bs[ii * 512]);
        }
        __syncthreads();
#pragma unroll
        for (int kk = 0; kk < 2; ++kk) {
            bf16x8 af[4], bq[4];
#pragma unroll
            for (int mf = 0; mf < 4; ++mf) {
                int row = wm * 64 + mf * 16 + rl;
                af[mf] = *reinterpret_cast<const bf16x8*>(&As[row * 64 + (((kk * 4 + gg) ^ (row & 7)) << 3)]);
            }
#pragma unroll
            for (int nf = 0; nf < 4; ++nf) {
                int row = wn * 64 + nf * 16 + rl;
                bq[nf] = *reinterpret_cast<const bf16x8*>(&Bs[row * 64 + (((kk * 4 + gg) ^ (row & 7)) << 3)]);
            }
#pragma unroll
            for (int mf = 0; mf < 4; ++mf)
#pragma unroll
                for (int nf = 0; nf < 4; ++nf)
                    acc[mf][nf] = __builtin_amdgcn_mfma_f32_16x16x32_bf16(af[mf], bq[nf], acc[mf][nf], 0, 0, 0);
        }
        __syncthreads();
    }
#pragma unroll
    for (int mf = 0; mf < 4; ++mf) {
#pragma unroll
        for (int nf = 0; nf < 4; ++nf) {
            int col = n0 + wn * 64 + nf * 16 + rl;
#pragma unroll
            for (int r = 0; r < 4; ++r) {
                int row = m0 + wm * 64 + mf * 16 + gg * 4 + r;
                long idx = (long)row * ldc + col;
                float v = acc[mf][nf][r] * alpha;
                if (MASK) {
                    int jj = col - 2048;
                    bool vis = (col < 2048) || (((jj >> 9) == (row >> 9)) && (jj <= row));
                    if (!vis) v = -INFINITY;
                }
                if (ADD) v += Ad[idx];
                if constexpr (sizeof(OUT) == 2) ((u16*)C)[idx] = (u16)bf16_1(v);
                else C[idx] = v;
            }
        }
    }
}

// ============ transpose-convert: W[K,N] fp32 -> WT[N,K] bf16 ============
__global__ void convT_kernel(const float* __restrict__ W, int ldw, int n0,
                             u16* __restrict__ WT, int ldk) {
    __shared__ float tile[64][65];
    int t = threadIdx.x;
    int c = t & 63, r4 = t >> 6;
    const float* src = W + (long)(blockIdx.y * 64 + r4) * ldw + n0 + blockIdx.x * 64 + c;
#pragma unroll
    for (int p = 0; p < 16; ++p)
        tile[r4 + p * 4][c] = src[(long)p * 4 * ldw];
    __syncthreads();
    int kp = t & 31, cc = t >> 5;
#pragma unroll
    for (int p = 0; p < 8; ++p) {
        int crow = cc + p * 8;
        float a = tile[kp * 2][crow], b = tile[kp * 2 + 1][crow];
        ((u32*)WT)[(((long)(blockIdx.x * 64 + crow) * ldk + blockIdx.y * 64) >> 1) + kp] = packbf(a, b);
    }
}

// ---------------- embedding gather ----------------
__global__ void embed_kernel(const int* __restrict__ ids, const float* __restrict__ emb,
                             float* __restrict__ x) {
    int idx = blockIdx.x * 256 + threadIdx.x;
    int s = idx >> 9, c = idx & 511;
    float4 v = *reinterpret_cast<const float4*>(emb + (long)ids[s] * 2048 + c * 4);
    *reinterpret_cast<float4*>(x + (long)s * 2048 + c * 4) = v;
}

// ---------------- RMSNorm: fp32 in -> bf16 out ----------------
__global__ void rmsnorm_kernel(const float* __restrict__ x, const float* __restrict__ w,
                               u16* __restrict__ o) {
    int row = blockIdx.x, t = threadIdx.x;
    const float* xr = x + (long)row * 2048;
    float4 v0 = *reinterpret_cast<const float4*>(xr + t * 4);
    float4 v1 = *reinterpret_cast<const float4*>(xr + 1024 + t * 4);
    float ss = v0.x * v0.x + v0.y * v0.y + v0.z * v0.z + v0.w * v0.w
             + v1.x * v1.x + v1.y * v1.y + v1.z * v1.z + v1.w * v1.w;
#pragma unroll
    for (int ofs = 32; ofs; ofs >>= 1) ss += __shfl_xor(ss, ofs);
    __shared__ float red[4];
    if ((t & 63) == 0) red[t >> 6] = ss;
    __syncthreads();
    ss = red[0] + red[1] + red[2] + red[3];
    float inv = 1.0f / sqrtf(ss * (1.0f / 2048.0f) + 1e-5f);
    float4 w0 = *reinterpret_cast<const float4*>(w + t * 4);
    float4 w1 = *reinterpret_cast<const float4*>(w + 1024 + t * 4);
    u32* op = (u32*)(o + (long)row * 2048);
    op[t * 2]           = packbf(v0.x * inv * w0.x, v0.y * inv * w0.y);
    op[t * 2 + 1]       = packbf(v0.z * inv * w0.z, v0.w * inv * w0.w);
    op[512 + t * 2]     = packbf(v1.x * inv * w1.x, v1.y * inv * w1.y);
    op[512 + t * 2 + 1] = packbf(v1.z * inv * w1.z, v1.w * inv * w1.w);
}

// ---------------- fused: x += p0 + p1 ; h = rmsnorm(x) * w ----------------
__global__ void rmsadd2_kernel(float* __restrict__ x, const float* __restrict__ p0,
                               const float* __restrict__ p1, const float* __restrict__ w,
                               u16* __restrict__ o) {
    int row = blockIdx.x, t = threadIdx.x;
    long base = (long)row * 2048;
    float4 v0 = *reinterpret_cast<const float4*>(x + base + t * 4);
    float4 v1 = *reinterpret_cast<const float4*>(x + base + 1024 + t * 4);
    float4 a0 = *reinterpret_cast<const float4*>(p0 + base + t * 4);
    float4 a1 = *reinterpret_cast<const float4*>(p0 + base + 1024 + t * 4);
    float4 b0 = *reinterpret_cast<const float4*>(p1 + base + t * 4);
    float4 b1 = *reinterpret_cast<const float4*>(p1 + base + 1024 + t * 4);
    v0.x += a0.x + b0.x; v0.y += a0.y + b0.y; v0.z += a0.z + b0.z; v0.w += a0.w + b0.w;
    v1.x += a1.x + b1.x; v1.y += a1.y + b1.y; v1.z += a1.z + b1.z; v1.w += a1.w + b1.w;
    *reinterpret_cast<float4*>(x + base + t * 4) = v0;
    *reinterpret_cast<float4*>(x + base + 1024 + t * 4) = v1;
    float ss = v0.x * v0.x + v0.y * v0.y + v0.z * v0.z + v0.w * v0.w
             + v1.x * v1.x + v1.y * v1.y + v1.z * v1.z + v1.w * v1.w;
#pragma unroll
    for (int ofs = 32; ofs; ofs >>= 1) ss += __shfl_xor(ss, ofs);
    __shared__ float red[4];
    if ((t & 63) == 0) red[t >> 6] = ss;
    __syncthreads();
    ss = red[0] + red[1] + red[2] + red[3];
    float inv = 1.0f / sqrtf(ss * (1.0f / 2048.0f) + 1e-5f);
    float4 w0 = *reinterpret_cast<const float4*>(w + t * 4);
    float4 w1 = *reinterpret_cast<const float4*>(w + 1024 + t * 4);
    u32* op = (u32*)(o + (long)row * 2048);
    op[t * 2]           = packbf(v0.x * inv * w0.x, v0.y * inv * w0.y);
    op[t * 2 + 1]       = packbf(v0.z * inv * w0.z, v0.w * inv * w0.w);
    op[512 + t * 2]     = packbf(v1.x * inv * w1.x, v1.y * inv * w1.y);
    op[512 + t * 2 + 1] = packbf(v1.z * inv * w1.z, v1.w * inv * w1.w);
}

// ---------------- RoPE on q (bf16, in place in qkv, pos = 2048+s) ----------------
__global__ void rope_q_kernel(u16* __restrict__ qkv) {
    int idx = blockIdx.x * 256 + threadIdx.x;  // 1024*16*64
    int fi = idx & 63;
    int hh = (idx >> 6) & 15;
    int s = idx >> 10;
    u16* p = qkv + (long)s * 3072 + hh * 128 + fi;
    float q0 = bf2f(p[0]), q1 = bf2f(p[64]);
    float inv = exp2f((float)fi * -0.20762050593046014f);  // 10000^(-fi/64)
    float ang = (float)(2048 + s) * inv;
    float sn, cs;
    sincosf(ang, &sn, &cs);
    p[0]  = (u16)bf16_1(q0 * cs - q1 * sn);
    p[64] = (u16)bf16_1(q1 * cs + q0 * sn);
}

// ---------------- build K [16][3072][128] bf16 (cache + repeated new, RoPE) ----------------
__global__ void build_k_kernel(const float* __restrict__ kc, const u16* __restrict__ qkv,
                               u16* __restrict__ kf) {
    int t = blockIdx.x * 256 + threadIdx.x;
    int hh = blockIdx.y;
    int fi = t & 63;
    int j = t >> 6;
    float k0, k1;
    if (j < 2048) {
        const float* kp = kc + ((long)hh * 2048 + j) * 128;
        k0 = kp[fi]; k1 = kp[fi + 64];
    } else {
        int s = j - 2048;
        const u16* kp = qkv + (long)s * 3072 + 2048 + (hh >> 2) * 128;
        k0 = bf2f(kp[fi]); k1 = bf2f(kp[fi + 64]);
    }
    float inv = exp2f((float)fi * -0.20762050593046014f);
    float ang = (float)j * inv;
    float sn, cs;
    sincosf(ang, &sn, &cs);
    u16* kd = kf + ((long)hh * 3072 + j) * 128;
    kd[fi]      = (u16)bf16_1(k0 * cs - k1 * sn);
    kd[fi + 64] = (u16)bf16_1(k1 * cs + k0 * sn);
}

// ---------------- build V^T [16][128][3072] bf16 via LDS transpose ----------------
__global__ void build_vT_kernel(const float* __restrict__ vc, const u16* __restrict__ qkv,
                                u16* __restrict__ vfT) {
    __shared__ u16 tile[64][137];
    int hh = blockIdx.y, j0 = blockIdx.x * 64;
    int t = threadIdx.x;
    int d = t & 127, jr = t >> 7;
#pragma unroll
    for (int p = 0; p < 32; ++p) {
        int j = jr + p * 2;
        int gj = j0 + j;
        float v;
        if (gj < 2048) v = vc[((long)hh * 2048 + gj) * 128 + d];
        else           v = bf2f(qkv[(long)(gj - 2048) * 3072 + 2560 + (hh >> 2) * 128 + d]);
        tile[j][d] = (u16)bf16_1(v);
    }
    __syncthreads();
    int jp = t & 31, dd = t >> 5;
#pragma unroll
    for (int p = 0; p < 16; ++p) {
        int d2 = dd + p * 8;
        u32 w = (u32)tile[jp * 2][d2] | ((u32)tile[jp * 2 + 1][d2] << 16);
        ((u32*)vfT)[((long)hh * 128 + d2) * 1536 + (j0 >> 1) + jp] = w;
    }
}

// ---------------- softmax in place on bf16 probs rows (mask pre-applied as -inf) --------
__global__ void softmax_kernel(u16* __restrict__ probs) {
    int i = blockIdx.x, hh = blockIdx.y, t = threadIdx.x;
    u32* row = (u32*)(probs + ((long)hh * 1024 + i) * 3072);
    float v[12];
    float mx = -1e30f;
#pragma unroll
    for (int it = 0; it < 6; ++it) {
        u32 wv = row[t + it * 256];
        float a = bf2f((u16)(wv & 0xffff)), b = bf2f((u16)(wv >> 16));
        v[2 * it] = a; v[2 * it + 1] = b;
        mx = fmaxf(mx, fmaxf(a, b));
    }
#pragma unroll
    for (int ofs = 32; ofs; ofs >>= 1) mx = fmaxf(mx, __shfl_xor(mx, ofs));
    __shared__ float red[4];
    if ((t & 63) == 0) red[t >> 6] = mx;
    __syncthreads();
    mx = fmaxf(fmaxf(red[0], red[1]), fmaxf(red[2], red[3]));
    float sum = 0.f;
#pragma unroll
    for (int k = 0; k < 12; ++k) {
        float e = __expf(v[k] - mx);
        v[k] = e;
        sum += e;
    }
#pragma unroll
    for (int ofs = 32; ofs; ofs >>= 1) sum += __shfl_xor(sum, ofs);
    __syncthreads();
    if ((t & 63) == 0) red[t >> 6] = sum;
    __syncthreads();
    sum = red[0] + red[1] + red[2] + red[3];
    float inv = 1.0f / sum;
#pragma unroll
    for (int it = 0; it < 6; ++it)
        row[t + it * 256] = packbf(v[2 * it] * inv, v[2 * it + 1] * inv);
}

// ---------------- SiLU(gate)*up on merged [1024][11264] buffer, in place into gate ------
__global__ void silu_mul_kernel(u32* __restrict__ gu) {
    int p = blockIdx.x * 256 + threadIdx.x;   // 0..2815
    int r = blockIdx.y;
    u32* rowp = gu + (long)r * 5632;
    u32 gv = rowp[p], uv = rowp[2816 + p];
    float g0 = bf2f((u16)(gv & 0xffff)), g1 = bf2f((u16)(gv >> 16));
    float u0 = bf2f((u16)(uv & 0xffff)), u1 = bf2f((u16)(uv >> 16));
    float r0 = (g0 / (1.0f + __expf(-g0))) * u0;
    float r1 = (g1 / (1.0f + __expf(-g1))) * u1;
    rowp[p] = packbf(r0, r1);
}

// ---------------- host ----------------
extern "C" void kernel_launch(void* const* d_in, const int* in_sizes, int n_in,
                              void* d_out, int out_size, void* d_ws, size_t ws_size,
                              hipStream_t stream) {
    const int*   ids   = (const int*)d_in[0];
    const float* kv    = (const float*)d_in[1];
    const float* emb   = (const float*)d_in[2];
    const float* Wq    = (const float*)d_in[3];
    const float* Wk    = (const float*)d_in[4];
    const float* Wv    = (const float*)d_in[5];
    const float* Wo    = (const float*)d_in[6];
    const float* ln1   = (const float*)d_in[7];
    const float* ln2   = (const float*)d_in[8];
    const float* Wg    = (const float*)d_in[9];
    const float* Wu    = (const float*)d_in[10];
    const float* Wd    = (const float*)d_in[11];
    const float* normw = (const float*)d_in[12];
    const float* lmh   = (const float*)d_in[13];
    float* out = (float*)d_out;
    (void)in_sizes; (void)n_in; (void)out_size; (void)ws_size;

    char* w = (char*)d_ws;
    u16*   wt    = (u16*)w;                       // per-layer bf16^T weights (90.2 MB) / lmT chunks
    float* x     = (float*)(w + 90177536);        // [1024,2048] fp32 residual
    u16*   h     = (u16*)(w + 98566144);          // [1024,2048] bf16
    u16*   qkv   = (u16*)(w + 102760448);         // [1024,3072] bf16 ; attn aliases (PV after scores)
    u16*   attn  = qkv;                           // [1024,2048] bf16
    u16*   kf    = (u16*)(w + 109051904);         // [16,3072,128] bf16
    u16*   vfT   = (u16*)(w + 121634816);         // [16,128,3072] bf16
    u16*   probs = (u16*)(w + 134217728);         // [16,1024,3072] bf16 (100.7 MB)
    u16*   gu    = probs;                         // [1024,11264] bf16 (after attention done)
    float* partWo = (float*)(w + 134217728);      // 2x[1024,2048] fp32 (after PV)
    float* partWd = (float*)(w + 157286400);      // 2x[1024,2048] fp32 (after gu)
    // total ws use: 234,881,024 B (== round-1-proven bound)

    u16* qkvT = wt;                 // [3072][2048]
    u16* WoT  = wt + 6291456;       // [2048][2048]
    u16* guT  = wt + 10485760;      // [11264][2048]
    u16* WdT  = wt + 33554432;      // [2048][5632]
    u16* lmT  = wt;                 // [16000][2048] per chunk (after layers)

    const float scale = 0.08838834764831845f;

    embed_kernel<<<2048, 256, 0, stream>>>(ids, emb, x);
    rmsnorm_kernel<<<1024, 256, 0, stream>>>(x, ln1, h);

    for (int l = 0; l < 2; ++l) {
        const float* Wq_l = Wq + (long)l * 2048 * 2048;
        const float* Wk_l = Wk + (long)l * 2048 * 512;
        const float* Wv_l = Wv + (long)l * 2048 * 512;
        const float* Wo_l = Wo + (long)l * 2048 * 2048;
        const float* Wg_l = Wg + (long)l * 2048 * 5632;
        const float* Wu_l = Wu + (long)l * 2048 * 5632;
        const float* Wd_l = Wd + (long)l * 5632 * 2048;
        const float* kc = kv + (long)l * 16 * 2048 * 128;
        const float* vc = kv + (long)(2 + l) * 16 * 2048 * 128;

        convT_kernel<<<dim3(32, 32), 256, 0, stream>>>(Wq_l, 2048, 0, qkvT, 2048);
        convT_kernel<<<dim3(8, 32),  256, 0, stream>>>(Wk_l, 512,  0, qkvT + 2048 * 2048, 2048);
        convT_kernel<<<dim3(8, 32),  256, 0, stream>>>(Wv_l, 512,  0, qkvT + 2560 * 2048, 2048);
        convT_kernel<<<dim3(32, 32), 256, 0, stream>>>(Wo_l, 2048, 0, WoT, 2048);
        convT_kernel<<<dim3(88, 32), 256, 0, stream>>>(Wg_l, 5632, 0, guT, 2048);
        convT_kernel<<<dim3(88, 32), 256, 0, stream>>>(Wu_l, 5632, 0, guT + 5632 * 2048, 2048);
        convT_kernel<<<dim3(32, 88), 256, 0, stream>>>(Wd_l, 2048, 0, WdT, 5632);

        // fused QKV projection: [1024,3072]
        bgemm_kernel<u16, false, false><<<dim3(8, 24, 1), 256, 0, stream>>>(
            h, 2048, 0, qkvT, 2048, 0, qkv, 3072, 0, nullptr, 2048, 1.0f);
        rope_q_kernel<<<4096, 256, 0, stream>>>(qkv);
        build_k_kernel<<<dim3(768, 16), 256, 0, stream>>>(kc, qkv, kf);
        build_vT_kernel<<<dim3(48, 16), 256, 0, stream>>>(vc, qkv, vfT);

        // masked scores -> bf16 probs buffer, all 1024 q rows, 16 heads
        bgemm_kernel<u16, false, true><<<dim3(8, 24, 16), 256, 0, stream>>>(
            qkv, 3072, 128, kf, 128, (long)3072 * 128,
            probs, 3072, (long)1024 * 3072, nullptr, 128, scale);
        softmax_kernel<<<dim3(1024, 16), 256, 0, stream>>>(probs);
        bgemm_kernel<u16, false, false><<<dim3(8, 1, 16), 256, 0, stream>>>(
            probs, 3072, (long)1024 * 3072, vfT, 3072, (long)128 * 3072,
            attn, 2048, 128, nullptr, 3072, 1.0f);

        // Wo with split-K (z = k-slice), partials then fused add+rmsnorm(ln2)
        bgemm_kernel<float, false, false><<<dim3(8, 16, 2), 256, 0, stream>>>(
            attn, 2048, 1024, WoT, 2048, 1024,
            partWo, 2048, (long)1024 * 2048, nullptr, 1024, 1.0f);
        rmsadd2_kernel<<<1024, 256, 0, stream>>>(x, partWo, partWo + 2097152, ln2 + l * 2048, h);

        // fused gate+up: [1024,11264]
        bgemm_kernel<u16, false, false><<<dim3(8, 88, 1), 256, 0, stream>>>(
            h, 2048, 0, guT, 2048, 0, gu, 11264, 0, nullptr, 2048, 1.0f);
        silu_mul_kernel<<<dim3(11, 1024), 256, 0, stream>>>((u32*)gu);

        // Wd with split-K, partials then fused add+rmsnorm(next norm weight)
        bgemm_kernel<float, false, false><<<dim3(8, 16, 2), 256, 0, stream>>>(
            gu, 11264, 2816, WdT, 5632, 2816,
            partWd, 2048, (long)1024 * 2048, nullptr, 2816, 1.0f);
        rmsadd2_kernel<<<1024, 256, 0, stream>>>(
            x, partWd, partWd + 2097152, (l == 0) ? (ln1 + 2048) : normw, h);
    }

    // lm_head in 2 chunks of 16000 columns
    for (int c = 0; c < 2; ++c) {
        int c0 = c * 16000;
        convT_kernel<<<dim3(250, 32), 256, 0, stream>>>(lmh, 32000, c0, lmT, 2048);
        bgemm_kernel<float, false, false><<<dim3(8, 125, 1), 256, 0, stream>>>(
            h, 2048, 0, lmT, 2048, 0, out + c0, 32000, 0, nullptr, 2048, 1.0f);
    }
}

// Round 4
// 1048.807 us; speedup vs baseline: 7.6850x; 1.1112x over previous
//
#include <hip/hip_runtime.h>
#include <hip/hip_bf16.h>
#include <stdint.h>

typedef __attribute__((ext_vector_type(8))) short bf16x8;
typedef __attribute__((ext_vector_type(4))) float f32x4;
typedef unsigned int u32;
typedef unsigned short u16;

// ---------------- helpers ----------------
__device__ __forceinline__ u32 bf16_1(float x) {
    u32 u = __float_as_uint(x);
    return (u + 0x7fffu + ((u >> 16) & 1u)) >> 16;   // RNE to bf16
}
__device__ __forceinline__ u32 packbf(float a, float b) {
    return bf16_1(a) | (bf16_1(b) << 16);
}
__device__ __forceinline__ float bf2f(u16 v) {
    return __uint_as_float(((u32)v) << 16);
}
// XOR-swizzle involution for 128-elem (16-chunk) bf16 rows; same map on write & read.
__device__ __forceinline__ int swz16(int row, int chunk) {
    return (chunk & 8) | ((chunk ^ row) & 7);
}

typedef const __attribute__((address_space(1))) u32* gptr_t;
typedef __attribute__((address_space(3))) u32* lptr_t;
__device__ __forceinline__ void gload16(const u16* g, u16* l) {
    __builtin_amdgcn_global_load_lds((gptr_t)g, (lptr_t)l, 16, 0, 0);
}

// ============ bf16 GEMM: C[M,N] = A[M,K] @ B^T[N,K] ============
// 128x128 tile, BK=64, global_load_lds staging, XOR-swizzled LDS (proven r2/r3).
template<typename OUT>
__global__ __launch_bounds__(256) void bgemm_kernel(
    const u16* __restrict__ A, int lda, long zA,
    const u16* __restrict__ B, int ldb, long zB,
    OUT* __restrict__ C, int ldc, long zC,
    int K)
{
    __shared__ __align__(16) u16 As[128 * 64];
    __shared__ __align__(16) u16 Bs[128 * 64];
    const int z = blockIdx.z;
    A += (long)z * zA;
    B += (long)z * zB;
    C += (long)z * zC;

    const int m0 = blockIdx.x * 128, n0 = blockIdx.y * 128;
    const int tid = threadIdx.x;
    const int lane = tid & 63, wave = tid >> 6;
    const int wm = wave & 1, wn = wave >> 1;
    const int rl = lane & 15, gg = lane >> 4;
    const int srow = lane >> 3, schunk = lane & 7;

    f32x4 zero4 = {0.f, 0.f, 0.f, 0.f};
    f32x4 acc[4][4];
#pragma unroll
    for (int i = 0; i < 4; ++i)
#pragma unroll
        for (int j = 0; j < 4; ++j) acc[i][j] = zero4;

    for (int k0 = 0; k0 < K; k0 += 64) {
#pragma unroll
        for (int it = 0; it < 4; ++it) {
            int ii = wave * 4 + it;
            int row = ii * 8 + srow;
            int sc_ = (schunk ^ (row & 7)) << 3;
            gload16(A + (long)(m0 + row) * lda + k0 + sc_, &As[ii * 512]);
            gload16(B + (long)(n0 + row) * ldb + k0 + sc_, &Bs[ii * 512]);
        }
        __syncthreads();
#pragma unroll
        for (int kk = 0; kk < 2; ++kk) {
            bf16x8 af[4], bq[4];
#pragma unroll
            for (int mf = 0; mf < 4; ++mf) {
                int row = wm * 64 + mf * 16 + rl;
                af[mf] = *reinterpret_cast<const bf16x8*>(&As[row * 64 + (((kk * 4 + gg) ^ (row & 7)) << 3)]);
            }
#pragma unroll
            for (int nf = 0; nf < 4; ++nf) {
                int row = wn * 64 + nf * 16 + rl;
                bq[nf] = *reinterpret_cast<const bf16x8*>(&Bs[row * 64 + (((kk * 4 + gg) ^ (row & 7)) << 3)]);
            }
#pragma unroll
            for (int mf = 0; mf < 4; ++mf)
#pragma unroll
                for (int nf = 0; nf < 4; ++nf)
                    acc[mf][nf] = __builtin_amdgcn_mfma_f32_16x16x32_bf16(af[mf], bq[nf], acc[mf][nf], 0, 0, 0);
        }
        __syncthreads();
    }
#pragma unroll
    for (int mf = 0; mf < 4; ++mf) {
#pragma unroll
        for (int nf = 0; nf < 4; ++nf) {
            int col = n0 + wn * 64 + nf * 16 + rl;
#pragma unroll
            for (int r = 0; r < 4; ++r) {
                int row = m0 + wm * 64 + mf * 16 + gg * 4 + r;
                long idx = (long)row * ldc + col;
                float v = acc[mf][nf][r];
                if constexpr (sizeof(OUT) == 2) ((u16*)C)[idx] = (u16)bf16_1(v);
                else C[idx] = v;
            }
        }
    }
}

// ============ flash attention: S^T=K·Q^T, online softmax, O^T=V^T·P^T ============
// grid (32 q-tiles of 32 rows, 16 heads), 128 threads (2 waves, 16 q-rows each).
// kv-tile = 128. LDS: Ks[128][128] + Vs[128][128] + Ps[32][128] = 72 KB.
__global__ __launch_bounds__(128) void flash_kernel(
    const u16* __restrict__ qkv, const u16* __restrict__ kf,
    const u16* __restrict__ vfT, u16* __restrict__ attn)
{
    __shared__ __align__(16) u16 Ks[128 * 128];
    __shared__ __align__(16) u16 Vs[128 * 128];
    __shared__ __align__(16) u16 Ps[32 * 128];
    const int h = blockIdx.y;
    const int q0 = blockIdx.x * 32;
    const int t = threadIdx.x;
    const int lane = t & 63, w = t >> 6;
    const int rl = lane & 15, gg = lane >> 4;
    const int qg = q0 + w * 16 + rl;       // this lane's q column in S^T/O^T acc
    const int qrow = w * 16 + rl;          // local q row for Ps
    const int srow = t >> 4, schunk = t & 15;

    // Q fragments hoisted to registers (k-slot map d = kk*32+gg*8+i, same as K)
    bf16x8 qf[4];
#pragma unroll
    for (int kk = 0; kk < 4; ++kk)
        qf[kk] = *reinterpret_cast<const bf16x8*>(qkv + (long)qg * 3072 + h * 128 + kk * 32 + gg * 8);

    f32x4 o[8];
#pragma unroll
    for (int i = 0; i < 8; ++i) o[i] = (f32x4){0.f, 0.f, 0.f, 0.f};
    float m = -INFINITY, l = 0.f;

    const int cs = q0 & ~511;                       // chunk start of this q-tile
    const int ntiles = 16 + ((q0 - cs + 159) >> 7); // 16 cache tiles + 1..4 local

    for (int tt = 0; tt < ntiles; ++tt) {
        const int tb = (tt < 16) ? tt * 128 : (2048 + cs + (tt - 16) * 128);
        // ---- stage K,V tile (linear LDS dest, inverse-swizzled source) ----
#pragma unroll
        for (int i = 0; i < 16; ++i) {
            int row = i * 8 + srow;
            int cw = swz16(row, schunk) * 8;
            gload16(kf + ((long)(h * 3072 + tb + row)) * 128 + cw, &Ks[i * 1024 + w * 512]);
        }
#pragma unroll
        for (int i = 0; i < 16; ++i) {
            int row = i * 8 + srow;
            int cw = swz16(row, schunk) * 8;
            gload16(vfT + ((long)(h * 128 + row)) * 3072 + tb + cw, &Vs[i * 1024 + w * 512]);
        }
        __syncthreads();
        // ---- S^T[kv][q] = K · Q^T (contraction over d=128) ----
        f32x4 s[8];
#pragma unroll
        for (int f = 0; f < 8; ++f) s[f] = (f32x4){0.f, 0.f, 0.f, 0.f};
#pragma unroll
        for (int kk = 0; kk < 4; ++kk) {
#pragma unroll
            for (int f = 0; f < 8; ++f) {
                int row = f * 16 + rl;
                bf16x8 kfrag = *reinterpret_cast<const bf16x8*>(
                    &Ks[row * 128 + swz16(row, kk * 4 + gg) * 8]);
                s[f] = __builtin_amdgcn_mfma_f32_16x16x32_bf16(kfrag, qf[kk], s[f], 0, 0, 0);
            }
        }
        // ---- scale + (local) mask + online softmax ----
        float tm = -INFINITY;
#pragma unroll
        for (int f = 0; f < 8; ++f) {
#pragma unroll
            for (int r = 0; r < 4; ++r) {
                float v = s[f][r] * 0.08838834764831845f;
                if (tt >= 16) {
                    int jloc = (tb - 2048) + f * 16 + gg * 4 + r;
                    if (jloc > qg) v = -INFINITY;   // block-causal within chunk
                }
                s[f][r] = v;
                tm = fmaxf(tm, v);
            }
        }
        tm = fmaxf(tm, __shfl_xor(tm, 16));
        tm = fmaxf(tm, __shfl_xor(tm, 32));
        float mnew = fmaxf(m, tm);
        float alpha = __expf(m - mnew);   // first tile: exp(-inf)=0
        m = mnew;
        float ts = 0.f;
#pragma unroll
        for (int f = 0; f < 8; ++f) {
#pragma unroll
            for (int r = 0; r < 4; ++r) {
                float e = __expf(s[f][r] - m);
                s[f][r] = e;
                ts += e;
            }
        }
        ts += __shfl_xor(ts, 16);
        ts += __shfl_xor(ts, 32);
        l = l * alpha + ts;
#pragma unroll
        for (int i = 0; i < 8; ++i)
#pragma unroll
            for (int r = 0; r < 4; ++r) o[i][r] *= alpha;
        // ---- P -> Ps (bf16, wave-private rows, swizzled) ----
#pragma unroll
        for (int f = 0; f < 8; ++f) {
            int kvb = f * 16 + gg * 4;
            u32* dst = (u32*)&Ps[qrow * 128 + swz16(qrow, kvb >> 3) * 8 + (kvb & 7)];
            dst[0] = packbf(s[f][0], s[f][1]);
            dst[1] = packbf(s[f][2], s[f][3]);
        }
        // ---- O^T[d][q] += V^T · P^T (contraction over kv=128) ----
#pragma unroll
        for (int kk = 0; kk < 4; ++kk) {
            bf16x8 pfrag = *reinterpret_cast<const bf16x8*>(
                &Ps[qrow * 128 + swz16(qrow, kk * 4 + gg) * 8]);
#pragma unroll
            for (int fd = 0; fd < 8; ++fd) {
                int row = fd * 16 + rl;
                bf16x8 vfrag = *reinterpret_cast<const bf16x8*>(
                    &Vs[row * 128 + swz16(row, kk * 4 + gg) * 8]);
                o[fd] = __builtin_amdgcn_mfma_f32_16x16x32_bf16(vfrag, pfrag, o[fd], 0, 0, 0);
            }
        }
        __syncthreads();
    }
    // ---- epilogue: attn[q][h*128+d] = O^T[d][q] / l ----
    float inv = 1.0f / l;
    u32* orow = (u32*)(attn + (long)qg * 2048 + h * 128);
#pragma unroll
    for (int fd = 0; fd < 8; ++fd) {
        int d0 = fd * 16 + gg * 4;
        orow[d0 >> 1]       = packbf(o[fd][0] * inv, o[fd][1] * inv);
        orow[(d0 >> 1) + 1] = packbf(o[fd][2] * inv, o[fd][3] * inv);
    }
}

// ============ transpose-convert: W[K,N] fp32 -> WT[N,K] bf16 ============
__global__ void convT_kernel(const float* __restrict__ W, int ldw, int n0,
                             u16* __restrict__ WT, int ldk) {
    __shared__ float tile[64][65];
    int t = threadIdx.x;
    int c = t & 63, r4 = t >> 6;
    const float* src = W + (long)(blockIdx.y * 64 + r4) * ldw + n0 + blockIdx.x * 64 + c;
#pragma unroll
    for (int p = 0; p < 16; ++p)
        tile[r4 + p * 4][c] = src[(long)p * 4 * ldw];
    __syncthreads();
    int kp = t & 31, cc = t >> 5;
#pragma unroll
    for (int p = 0; p < 8; ++p) {
        int crow = cc + p * 8;
        float a = tile[kp * 2][crow], b = tile[kp * 2 + 1][crow];
        ((u32*)WT)[(((long)(blockIdx.x * 64 + crow) * ldk + blockIdx.y * 64) >> 1) + kp] = packbf(a, b);
    }
}

// ---------------- embedding gather ----------------
__global__ void embed_kernel(const int* __restrict__ ids, const float* __restrict__ emb,
                             float* __restrict__ x) {
    int idx = blockIdx.x * 256 + threadIdx.x;
    int s = idx >> 9, c = idx & 511;
    float4 v = *reinterpret_cast<const float4*>(emb + (long)ids[s] * 2048 + c * 4);
    *reinterpret_cast<float4*>(x + (long)s * 2048 + c * 4) = v;
}

// ---------------- RMSNorm: fp32 in -> bf16 out ----------------
__global__ void rmsnorm_kernel(const float* __restrict__ x, const float* __restrict__ w,
                               u16* __restrict__ o) {
    int row = blockIdx.x, t = threadIdx.x;
    const float* xr = x + (long)row * 2048;
    float4 v0 = *reinterpret_cast<const float4*>(xr + t * 4);
    float4 v1 = *reinterpret_cast<const float4*>(xr + 1024 + t * 4);
    float ss = v0.x * v0.x + v0.y * v0.y + v0.z * v0.z + v0.w * v0.w
             + v1.x * v1.x + v1.y * v1.y + v1.z * v1.z + v1.w * v1.w;
#pragma unroll
    for (int ofs = 32; ofs; ofs >>= 1) ss += __shfl_xor(ss, ofs);
    __shared__ float red[4];
    if ((t & 63) == 0) red[t >> 6] = ss;
    __syncthreads();
    ss = red[0] + red[1] + red[2] + red[3];
    float inv = 1.0f / sqrtf(ss * (1.0f / 2048.0f) + 1e-5f);
    float4 w0 = *reinterpret_cast<const float4*>(w + t * 4);
    float4 w1 = *reinterpret_cast<const float4*>(w + 1024 + t * 4);
    u32* op = (u32*)(o + (long)row * 2048);
    op[t * 2]           = packbf(v0.x * inv * w0.x, v0.y * inv * w0.y);
    op[t * 2 + 1]       = packbf(v0.z * inv * w0.z, v0.w * inv * w0.w);
    op[512 + t * 2]     = packbf(v1.x * inv * w1.x, v1.y * inv * w1.y);
    op[512 + t * 2 + 1] = packbf(v1.z * inv * w1.z, v1.w * inv * w1.w);
}

// ---------------- fused: x += p0 + p1 ; h = rmsnorm(x) * w ----------------
__global__ void rmsadd2_kernel(float* __restrict__ x, const float* __restrict__ p0,
                               const float* __restrict__ p1, const float* __restrict__ w,
                               u16* __restrict__ o) {
    int row = blockIdx.x, t = threadIdx.x;
    long base = (long)row * 2048;
    float4 v0 = *reinterpret_cast<const float4*>(x + base + t * 4);
    float4 v1 = *reinterpret_cast<const float4*>(x + base + 1024 + t * 4);
    float4 a0 = *reinterpret_cast<const float4*>(p0 + base + t * 4);
    float4 a1 = *reinterpret_cast<const float4*>(p0 + base + 1024 + t * 4);
    float4 b0 = *reinterpret_cast<const float4*>(p1 + base + t * 4);
    float4 b1 = *reinterpret_cast<const float4*>(p1 + base + 1024 + t * 4);
    v0.x += a0.x + b0.x; v0.y += a0.y + b0.y; v0.z += a0.z + b0.z; v0.w += a0.w + b0.w;
    v1.x += a1.x + b1.x; v1.y += a1.y + b1.y; v1.z += a1.z + b1.z; v1.w += a1.w + b1.w;
    *reinterpret_cast<float4*>(x + base + t * 4) = v0;
    *reinterpret_cast<float4*>(x + base + 1024 + t * 4) = v1;
    float ss = v0.x * v0.x + v0.y * v0.y + v0.z * v0.z + v0.w * v0.w
             + v1.x * v1.x + v1.y * v1.y + v1.z * v1.z + v1.w * v1.w;
#pragma unroll
    for (int ofs = 32; ofs; ofs >>= 1) ss += __shfl_xor(ss, ofs);
    __shared__ float red[4];
    if ((t & 63) == 0) red[t >> 6] = ss;
    __syncthreads();
    ss = red[0] + red[1] + red[2] + red[3];
    float inv = 1.0f / sqrtf(ss * (1.0f / 2048.0f) + 1e-5f);
    float4 w0 = *reinterpret_cast<const float4*>(w + t * 4);
    float4 w1 = *reinterpret_cast<const float4*>(w + 1024 + t * 4);
    u32* op = (u32*)(o + (long)row * 2048);
    op[t * 2]           = packbf(v0.x * inv * w0.x, v0.y * inv * w0.y);
    op[t * 2 + 1]       = packbf(v0.z * inv * w0.z, v0.w * inv * w0.w);
    op[512 + t * 2]     = packbf(v1.x * inv * w1.x, v1.y * inv * w1.y);
    op[512 + t * 2 + 1] = packbf(v1.z * inv * w1.z, v1.w * inv * w1.w);
}

// ---------------- RoPE on q (bf16, in place in qkv, pos = 2048+s) ----------------
__global__ void rope_q_kernel(u16* __restrict__ qkv) {
    int idx = blockIdx.x * 256 + threadIdx.x;  // 1024*16*64
    int fi = idx & 63;
    int hh = (idx >> 6) & 15;
    int s = idx >> 10;
    u16* p = qkv + (long)s * 3072 + hh * 128 + fi;
    float q0 = bf2f(p[0]), q1 = bf2f(p[64]);
    float inv = exp2f((float)fi * -0.20762050593046014f);  // 10000^(-fi/64)
    float ang = (float)(2048 + s) * inv;
    float sn, cs;
    sincosf(ang, &sn, &cs);
    p[0]  = (u16)bf16_1(q0 * cs - q1 * sn);
    p[64] = (u16)bf16_1(q1 * cs + q0 * sn);
}

// ---------------- build K [16][3072][128] bf16 (cache + repeated new, RoPE) ----------------
__global__ void build_k_kernel(const float* __restrict__ kc, const u16* __restrict__ qkv,
                               u16* __restrict__ kf) {
    int t = blockIdx.x * 256 + threadIdx.x;
    int hh = blockIdx.y;
    int fi = t & 63;
    int j = t >> 6;
    float k0, k1;
    if (j < 2048) {
        const float* kp = kc + ((long)hh * 2048 + j) * 128;
        k0 = kp[fi]; k1 = kp[fi + 64];
    } else {
        int s = j - 2048;
        const u16* kp = qkv + (long)s * 3072 + 2048 + (hh >> 2) * 128;
        k0 = bf2f(kp[fi]); k1 = bf2f(kp[fi + 64]);
    }
    float inv = exp2f((float)fi * -0.20762050593046014f);
    float ang = (float)j * inv;
    float sn, cs;
    sincosf(ang, &sn, &cs);
    u16* kd = kf + ((long)hh * 3072 + j) * 128;
    kd[fi]      = (u16)bf16_1(k0 * cs - k1 * sn);
    kd[fi + 64] = (u16)bf16_1(k1 * cs + k0 * sn);
}

// ---------------- build V^T [16][128][3072] bf16 via LDS transpose ----------------
__global__ void build_vT_kernel(const float* __restrict__ vc, const u16* __restrict__ qkv,
                                u16* __restrict__ vfT) {
    __shared__ u16 tile[64][137];
    int hh = blockIdx.y, j0 = blockIdx.x * 64;
    int t = threadIdx.x;
    int d = t & 127, jr = t >> 7;
#pragma unroll
    for (int p = 0; p < 32; ++p) {
        int j = jr + p * 2;
        int gj = j0 + j;
        float v;
        if (gj < 2048) v = vc[((long)hh * 2048 + gj) * 128 + d];
        else           v = bf2f(qkv[(long)(gj - 2048) * 3072 + 2560 + (hh >> 2) * 128 + d]);
        tile[j][d] = (u16)bf16_1(v);
    }
    __syncthreads();
    int jp = t & 31, dd = t >> 5;
#pragma unroll
    for (int p = 0; p < 16; ++p) {
        int d2 = dd + p * 8;
        u32 w = (u32)tile[jp * 2][d2] | ((u32)tile[jp * 2 + 1][d2] << 16);
        ((u32*)vfT)[((long)hh * 128 + d2) * 1536 + (j0 >> 1) + jp] = w;
    }
}

// ---------------- SiLU(gate)*up on merged [1024][11264] buffer, in place into gate ------
__global__ void silu_mul_kernel(u32* __restrict__ gu) {
    int p = blockIdx.x * 256 + threadIdx.x;   // 0..2815
    int r = blockIdx.y;
    u32* rowp = gu + (long)r * 5632;
    u32 gv = rowp[p], uv = rowp[2816 + p];
    float g0 = bf2f((u16)(gv & 0xffff)), g1 = bf2f((u16)(gv >> 16));
    float u0 = bf2f((u16)(uv & 0xffff)), u1 = bf2f((u16)(uv >> 16));
    float r0 = (g0 / (1.0f + __expf(-g0))) * u0;
    float r1 = (g1 / (1.0f + __expf(-g1))) * u1;
    rowp[p] = packbf(r0, r1);
}

// ---------------- host ----------------
extern "C" void kernel_launch(void* const* d_in, const int* in_sizes, int n_in,
                              void* d_out, int out_size, void* d_ws, size_t ws_size,
                              hipStream_t stream) {
    const int*   ids   = (const int*)d_in[0];
    const float* kv    = (const float*)d_in[1];
    const float* emb   = (const float*)d_in[2];
    const float* Wq    = (const float*)d_in[3];
    const float* Wk    = (const float*)d_in[4];
    const float* Wv    = (const float*)d_in[5];
    const float* Wo    = (const float*)d_in[6];
    const float* ln1   = (const float*)d_in[7];
    const float* ln2   = (const float*)d_in[8];
    const float* Wg    = (const float*)d_in[9];
    const float* Wu    = (const float*)d_in[10];
    const float* Wd    = (const float*)d_in[11];
    const float* normw = (const float*)d_in[12];
    const float* lmh   = (const float*)d_in[13];
    float* out = (float*)d_out;
    (void)in_sizes; (void)n_in; (void)out_size; (void)ws_size;

    char* w = (char*)d_ws;
    u16*   wt     = (u16*)w;                      // per-layer bf16^T weights (90.2 MB)
    float* x      = (float*)(w + 90177536);       // [1024,2048] fp32 residual
    u16*   h      = (u16*)(w + 98566144);         // [1024,2048] bf16
    u16*   qkv    = (u16*)(w + 102760448);        // [1024,3072] bf16 (layers only)
    u16*   kf     = (u16*)(w + 109051904);        // [16,3072,128] bf16
    u16*   vfT    = (u16*)(w + 121634816);        // [16,128,3072] bf16
    float* partWo = (float*)(w + 134217728);      // 2x[1024,2048] fp32
    u16*   gu     = (u16*)(w + 134217728);        // [1024,11264] bf16 (after Wo reduce)
    float* partWd = (float*)(w + 157286400);      // 2x[1024,2048] fp32
    u16*   attn   = (u16*)(w + 174063616);        // [1024,2048] bf16 (separate: flash reads qkv!)
    u16*   lmT    = (u16*)(w + 102760448);        // [32000][2048] bf16 post-layers (131 MB)

    u16* qkvT = wt;                 // [3072][2048]
    u16* WoT  = wt + 6291456;       // [2048][2048]
    u16* guT  = wt + 10485760;      // [11264][2048]
    u16* WdT  = wt + 33554432;      // [2048][5632]

    embed_kernel<<<2048, 256, 0, stream>>>(ids, emb, x);
    rmsnorm_kernel<<<1024, 256, 0, stream>>>(x, ln1, h);

    for (int l = 0; l < 2; ++l) {
        const float* Wq_l = Wq + (long)l * 2048 * 2048;
        const float* Wk_l = Wk + (long)l * 2048 * 512;
        const float* Wv_l = Wv + (long)l * 2048 * 512;
        const float* Wo_l = Wo + (long)l * 2048 * 2048;
        const float* Wg_l = Wg + (long)l * 2048 * 5632;
        const float* Wu_l = Wu + (long)l * 2048 * 5632;
        const float* Wd_l = Wd + (long)l * 5632 * 2048;
        const float* kc = kv + (long)l * 16 * 2048 * 128;
        const float* vc = kv + (long)(2 + l) * 16 * 2048 * 128;

        convT_kernel<<<dim3(32, 32), 256, 0, stream>>>(Wq_l, 2048, 0, qkvT, 2048);
        convT_kernel<<<dim3(8, 32),  256, 0, stream>>>(Wk_l, 512,  0, qkvT + 2048 * 2048, 2048);
        convT_kernel<<<dim3(8, 32),  256, 0, stream>>>(Wv_l, 512,  0, qkvT + 2560 * 2048, 2048);
        convT_kernel<<<dim3(32, 32), 256, 0, stream>>>(Wo_l, 2048, 0, WoT, 2048);
        convT_kernel<<<dim3(88, 32), 256, 0, stream>>>(Wg_l, 5632, 0, guT, 2048);
        convT_kernel<<<dim3(88, 32), 256, 0, stream>>>(Wu_l, 5632, 0, guT + 5632 * 2048, 2048);
        convT_kernel<<<dim3(32, 88), 256, 0, stream>>>(Wd_l, 2048, 0, WdT, 5632);

        // fused QKV projection: [1024,3072]
        bgemm_kernel<u16><<<dim3(8, 24, 1), 256, 0, stream>>>(
            h, 2048, 0, qkvT, 2048, 0, qkv, 3072, 0, 2048);
        rope_q_kernel<<<4096, 256, 0, stream>>>(qkv);
        build_k_kernel<<<dim3(768, 16), 256, 0, stream>>>(kc, qkv, kf);
        build_vT_kernel<<<dim3(48, 16), 256, 0, stream>>>(vc, qkv, vfT);

        // fused attention (scores+mask+softmax+PV)
        flash_kernel<<<dim3(32, 16), 128, 0, stream>>>(qkv, kf, vfT, attn);

        // Wo with split-K, partials then fused add+rmsnorm(ln2)
        bgemm_kernel<float><<<dim3(8, 16, 2), 256, 0, stream>>>(
            attn, 2048, 1024, WoT, 2048, 1024,
            partWo, 2048, (long)1024 * 2048, 1024);
        rmsadd2_kernel<<<1024, 256, 0, stream>>>(x, partWo, partWo + 2097152, ln2 + l * 2048, h);

        // fused gate+up: [1024,11264]
        bgemm_kernel<u16><<<dim3(8, 88, 1), 256, 0, stream>>>(
            h, 2048, 0, guT, 2048, 0, gu, 11264, 0, 2048);
        silu_mul_kernel<<<dim3(11, 1024), 256, 0, stream>>>((u32*)gu);

        // Wd with split-K, partials then fused add+rmsnorm(next norm weight)
        bgemm_kernel<float><<<dim3(8, 16, 2), 256, 0, stream>>>(
            gu, 11264, 2816, WdT, 5632, 2816,
            partWd, 2048, (long)1024 * 2048, 2816);
        rmsadd2_kernel<<<1024, 256, 0, stream>>>(
            x, partWd, partWd + 2097152, (l == 0) ? (ln1 + 2048) : normw, h);
    }

    // lm_head: single conversion + single GEMM (grid 8x250 = 2000 blocks)
    convT_kernel<<<dim3(500, 32), 256, 0, stream>>>(lmh, 32000, 0, lmT, 2048);
    bgemm_kernel<float><<<dim3(8, 250, 1), 256, 0, stream>>>(
        h, 2048, 0, lmT, 2048, 0, out, 32000, 0, 2048);
}

// Round 5
// 1025.236 us; speedup vs baseline: 7.8617x; 1.0230x over previous
//
#include <hip/hip_runtime.h>
#include <hip/hip_bf16.h>
#include <stdint.h>

typedef __attribute__((ext_vector_type(8))) short bf16x8;
typedef __attribute__((ext_vector_type(4))) float f32x4;
typedef unsigned int u32;
typedef unsigned short u16;

// ---------------- helpers ----------------
__device__ __forceinline__ u32 bf16_1(float x) {
    u32 u = __float_as_uint(x);
    return (u + 0x7fffu + ((u >> 16) & 1u)) >> 16;   // RNE to bf16
}
__device__ __forceinline__ u32 packbf(float a, float b) {
    return bf16_1(a) | (bf16_1(b) << 16);
}
__device__ __forceinline__ float bf2f(u16 v) {
    return __uint_as_float(((u32)v) << 16);
}
// XOR-swizzle involution for 128-elem (16-chunk) bf16 rows; same map on write & read.
__device__ __forceinline__ int swz16(int row, int chunk) {
    return (chunk & 8) | ((chunk ^ row) & 7);
}

typedef const __attribute__((address_space(1))) u32* gptr_t;
typedef __attribute__((address_space(3))) u32* lptr_t;
__device__ __forceinline__ void gload16(const u16* g, u16* l) {
    __builtin_amdgcn_global_load_lds((gptr_t)g, (lptr_t)l, 16, 0, 0);
}

// ============ bf16 GEMM: C[M,N] = A[M,K] @ B^T[N,K] ============
// 128x128 tile, BK=64, global_load_lds staging, XOR-swizzled LDS (proven r2-r4).
// XCD panel swizzle (T1): lin = xcd*(nwg/8)+pos decoded in (4-m-panel, n, m) order
// -> each XCD keeps a 2 MB A-panel L2-resident and streams its B-chunk once.
template<typename OUT>
__global__ __launch_bounds__(256) void bgemm_kernel(
    const u16* __restrict__ A, int lda, long zA,
    const u16* __restrict__ B, int ldb, long zB,
    OUT* __restrict__ C, int ldc, long zC,
    int K)
{
    __shared__ __align__(16) u16 As[128 * 64];
    __shared__ __align__(16) u16 Bs[128 * 64];
    const int z = blockIdx.z;
    A += (long)z * zA;
    B += (long)z * zB;
    C += (long)z * zC;

    const int gx = gridDim.x, gy = gridDim.y;
    int tm, tn;
    if (gx == 8) {                       // all our GEMM grids: bijective (nwg%8==0)
        int id = blockIdx.y * gx + blockIdx.x;
        int nwg8 = (gx * gy) >> 3;
        int lin = (id & 7) * nwg8 + (id >> 3);
        int span = gy << 2;              // gy * PM (PM=4)
        int pp = lin / span;
        int rem = lin - pp * span;
        tn = rem >> 2;
        tm = (pp << 2) + (rem & 3);
    } else { tm = blockIdx.x; tn = blockIdx.y; }
    const int m0 = tm * 128, n0 = tn * 128;

    const int tid = threadIdx.x;
    const int lane = tid & 63, wave = tid >> 6;
    const int wm = wave & 1, wn = wave >> 1;
    const int rl = lane & 15, gg = lane >> 4;
    const int srow = lane >> 3, schunk = lane & 7;

    f32x4 zero4 = {0.f, 0.f, 0.f, 0.f};
    f32x4 acc[4][4];
#pragma unroll
    for (int i = 0; i < 4; ++i)
#pragma unroll
        for (int j = 0; j < 4; ++j) acc[i][j] = zero4;

    for (int k0 = 0; k0 < K; k0 += 64) {
#pragma unroll
        for (int it = 0; it < 4; ++it) {
            int ii = wave * 4 + it;
            int row = ii * 8 + srow;
            int sc_ = (schunk ^ (row & 7)) << 3;
            gload16(A + (long)(m0 + row) * lda + k0 + sc_, &As[ii * 512]);
            gload16(B + (long)(n0 + row) * ldb + k0 + sc_, &Bs[ii * 512]);
        }
        __syncthreads();
#pragma unroll
        for (int kk = 0; kk < 2; ++kk) {
            bf16x8 af[4], bq[4];
#pragma unroll
            for (int mf = 0; mf < 4; ++mf) {
                int row = wm * 64 + mf * 16 + rl;
                af[mf] = *reinterpret_cast<const bf16x8*>(&As[row * 64 + (((kk * 4 + gg) ^ (row & 7)) << 3)]);
            }
#pragma unroll
            for (int nf = 0; nf < 4; ++nf) {
                int row = wn * 64 + nf * 16 + rl;
                bq[nf] = *reinterpret_cast<const bf16x8*>(&Bs[row * 64 + (((kk * 4 + gg) ^ (row & 7)) << 3)]);
            }
#pragma unroll
            for (int mf = 0; mf < 4; ++mf)
#pragma unroll
                for (int nf = 0; nf < 4; ++nf)
                    acc[mf][nf] = __builtin_amdgcn_mfma_f32_16x16x32_bf16(af[mf], bq[nf], acc[mf][nf], 0, 0, 0);
        }
        __syncthreads();
    }
#pragma unroll
    for (int mf = 0; mf < 4; ++mf) {
#pragma unroll
        for (int nf = 0; nf < 4; ++nf) {
            int col = n0 + wn * 64 + nf * 16 + rl;
#pragma unroll
            for (int r = 0; r < 4; ++r) {
                int row = m0 + wm * 64 + mf * 16 + gg * 4 + r;
                long idx = (long)row * ldc + col;
                float v = acc[mf][nf][r];
                if constexpr (sizeof(OUT) == 2) ((u16*)C)[idx] = (u16)bf16_1(v);
                else C[idx] = v;
            }
        }
    }
}

// ============ flash attention: S^T=K·Q^T, online softmax, O^T=V^T·P^T ============
// grid 512 blocks (swizzled: each XCD owns 2 heads -> K/V L2-resident), 128 threads.
// kv-tile = 128. LDS: Ks[128][128] + Vs[128][128] + Ps[32][128] = 72 KB.
__global__ __launch_bounds__(128) void flash_kernel(
    const u16* __restrict__ qkv, const u16* __restrict__ kf,
    const u16* __restrict__ vfT, u16* __restrict__ attn)
{
    __shared__ __align__(16) u16 Ks[128 * 128];
    __shared__ __align__(16) u16 Vs[128 * 128];
    __shared__ __align__(16) u16 Ps[32 * 128];
    // XCD swizzle: 512 blocks -> xcd owns lin [xcd*64, xcd*64+64) = 2 heads
    const int id = blockIdx.y * gridDim.x + blockIdx.x;
    const int lin = (id & 7) * 64 + (id >> 3);
    const int h = lin >> 5;
    const int q0 = (lin & 31) * 32;
    const int t = threadIdx.x;
    const int lane = t & 63, w = t >> 6;
    const int rl = lane & 15, gg = lane >> 4;
    const int qg = q0 + w * 16 + rl;       // this lane's q column in S^T/O^T acc
    const int qrow = w * 16 + rl;          // local q row for Ps
    const int srow = t >> 4, schunk = t & 15;

    // Q fragments hoisted to registers (k-slot map d = kk*32+gg*8+i, same as K)
    bf16x8 qf[4];
#pragma unroll
    for (int kk = 0; kk < 4; ++kk)
        qf[kk] = *reinterpret_cast<const bf16x8*>(qkv + (long)qg * 3072 + h * 128 + kk * 32 + gg * 8);

    f32x4 o[8];
#pragma unroll
    for (int i = 0; i < 8; ++i) o[i] = (f32x4){0.f, 0.f, 0.f, 0.f};
    float m = -INFINITY, l = 0.f;

    const int cs = q0 & ~511;                       // chunk start of this q-tile
    const int ntiles = 16 + ((q0 - cs + 159) >> 7); // 16 cache tiles + 1..4 local

    for (int tt = 0; tt < ntiles; ++tt) {
        const int tb = (tt < 16) ? tt * 128 : (2048 + cs + (tt - 16) * 128);
        // ---- stage K,V tile (linear LDS dest, inverse-swizzled source) ----
#pragma unroll
        for (int i = 0; i < 16; ++i) {
            int row = i * 8 + srow;
            int cw = swz16(row, schunk) * 8;
            gload16(kf + ((long)(h * 3072 + tb + row)) * 128 + cw, &Ks[i * 1024 + w * 512]);
        }
#pragma unroll
        for (int i = 0; i < 16; ++i) {
            int row = i * 8 + srow;
            int cw = swz16(row, schunk) * 8;
            gload16(vfT + ((long)(h * 128 + row)) * 3072 + tb + cw, &Vs[i * 1024 + w * 512]);
        }
        __syncthreads();
        // ---- S^T[kv][q] = K · Q^T (contraction over d=128) ----
        f32x4 s[8];
#pragma unroll
        for (int f = 0; f < 8; ++f) s[f] = (f32x4){0.f, 0.f, 0.f, 0.f};
#pragma unroll
        for (int kk = 0; kk < 4; ++kk) {
#pragma unroll
            for (int f = 0; f < 8; ++f) {
                int row = f * 16 + rl;
                bf16x8 kfrag = *reinterpret_cast<const bf16x8*>(
                    &Ks[row * 128 + swz16(row, kk * 4 + gg) * 8]);
                s[f] = __builtin_amdgcn_mfma_f32_16x16x32_bf16(kfrag, qf[kk], s[f], 0, 0, 0);
            }
        }
        // ---- scale + (local) mask + online softmax ----
        float tm = -INFINITY;
#pragma unroll
        for (int f = 0; f < 8; ++f) {
#pragma unroll
            for (int r = 0; r < 4; ++r) {
                float v = s[f][r] * 0.08838834764831845f;
                if (tt >= 16) {
                    int jloc = (tb - 2048) + f * 16 + gg * 4 + r;
                    if (jloc > qg) v = -INFINITY;   // block-causal within chunk
                }
                s[f][r] = v;
                tm = fmaxf(tm, v);
            }
        }
        tm = fmaxf(tm, __shfl_xor(tm, 16));
        tm = fmaxf(tm, __shfl_xor(tm, 32));
        float mnew = fmaxf(m, tm);
        float alpha = __expf(m - mnew);   // first tile: exp(-inf)=0
        m = mnew;
        float ts = 0.f;
#pragma unroll
        for (int f = 0; f < 8; ++f) {
#pragma unroll
            for (int r = 0; r < 4; ++r) {
                float e = __expf(s[f][r] - m);
                s[f][r] = e;
                ts += e;
            }
        }
        ts += __shfl_xor(ts, 16);
        ts += __shfl_xor(ts, 32);
        l = l * alpha + ts;
#pragma unroll
        for (int i = 0; i < 8; ++i)
#pragma unroll
            for (int r = 0; r < 4; ++r) o[i][r] *= alpha;
        // ---- P -> Ps (bf16, wave-private rows, swizzled) ----
#pragma unroll
        for (int f = 0; f < 8; ++f) {
            int kvb = f * 16 + gg * 4;
            u32* dst = (u32*)&Ps[qrow * 128 + swz16(qrow, kvb >> 3) * 8 + (kvb & 7)];
            dst[0] = packbf(s[f][0], s[f][1]);
            dst[1] = packbf(s[f][2], s[f][3]);
        }
        // ---- O^T[d][q] += V^T · P^T (contraction over kv=128) ----
#pragma unroll
        for (int kk = 0; kk < 4; ++kk) {
            bf16x8 pfrag = *reinterpret_cast<const bf16x8*>(
                &Ps[qrow * 128 + swz16(qrow, kk * 4 + gg) * 8]);
#pragma unroll
            for (int fd = 0; fd < 8; ++fd) {
                int row = fd * 16 + rl;
                bf16x8 vfrag = *reinterpret_cast<const bf16x8*>(
                    &Vs[row * 128 + swz16(row, kk * 4 + gg) * 8]);
                o[fd] = __builtin_amdgcn_mfma_f32_16x16x32_bf16(vfrag, pfrag, o[fd], 0, 0, 0);
            }
        }
        __syncthreads();
    }
    // ---- epilogue: attn[q][h*128+d] = O^T[d][q] / l ----
    float inv = 1.0f / l;
    u32* orow = (u32*)(attn + (long)qg * 2048 + h * 128);
#pragma unroll
    for (int fd = 0; fd < 8; ++fd) {
        int d0 = fd * 16 + gg * 4;
        orow[d0 >> 1]       = packbf(o[fd][0] * inv, o[fd][1] * inv);
        orow[(d0 >> 1) + 1] = packbf(o[fd][2] * inv, o[fd][3] * inv);
    }
}

// ============ transpose-convert: W[K,N] fp32 -> WT[N,K] bf16 ============
__global__ void convT_kernel(const float* __restrict__ W, int ldw, int n0,
                             u16* __restrict__ WT, int ldk) {
    __shared__ float tile[64][65];
    int t = threadIdx.x;
    int c = t & 63, r4 = t >> 6;
    const float* src = W + (long)(blockIdx.y * 64 + r4) * ldw + n0 + blockIdx.x * 64 + c;
#pragma unroll
    for (int p = 0; p < 16; ++p)
        tile[r4 + p * 4][c] = src[(long)p * 4 * ldw];
    __syncthreads();
    int kp = t & 31, cc = t >> 5;
#pragma unroll
    for (int p = 0; p < 8; ++p) {
        int crow = cc + p * 8;
        float a = tile[kp * 2][crow], b = tile[kp * 2 + 1][crow];
        ((u32*)WT)[(((long)(blockIdx.x * 64 + crow) * ldk + blockIdx.y * 64) >> 1) + kp] = packbf(a, b);
    }
}

// ---------------- embedding gather ----------------
__global__ void embed_kernel(const int* __restrict__ ids, const float* __restrict__ emb,
                             float* __restrict__ x) {
    int idx = blockIdx.x * 256 + threadIdx.x;
    int s = idx >> 9, c = idx & 511;
    float4 v = *reinterpret_cast<const float4*>(emb + (long)ids[s] * 2048 + c * 4);
    *reinterpret_cast<float4*>(x + (long)s * 2048 + c * 4) = v;
}

// ---------------- RMSNorm: fp32 in -> bf16 out ----------------
__global__ void rmsnorm_kernel(const float* __restrict__ x, const float* __restrict__ w,
                               u16* __restrict__ o) {
    int row = blockIdx.x, t = threadIdx.x;
    const float* xr = x + (long)row * 2048;
    float4 v0 = *reinterpret_cast<const float4*>(xr + t * 4);
    float4 v1 = *reinterpret_cast<const float4*>(xr + 1024 + t * 4);
    float ss = v0.x * v0.x + v0.y * v0.y + v0.z * v0.z + v0.w * v0.w
             + v1.x * v1.x + v1.y * v1.y + v1.z * v1.z + v1.w * v1.w;
#pragma unroll
    for (int ofs = 32; ofs; ofs >>= 1) ss += __shfl_xor(ss, ofs);
    __shared__ float red[4];
    if ((t & 63) == 0) red[t >> 6] = ss;
    __syncthreads();
    ss = red[0] + red[1] + red[2] + red[3];
    float inv = 1.0f / sqrtf(ss * (1.0f / 2048.0f) + 1e-5f);
    float4 w0 = *reinterpret_cast<const float4*>(w + t * 4);
    float4 w1 = *reinterpret_cast<const float4*>(w + 1024 + t * 4);
    u32* op = (u32*)(o + (long)row * 2048);
    op[t * 2]           = packbf(v0.x * inv * w0.x, v0.y * inv * w0.y);
    op[t * 2 + 1]       = packbf(v0.z * inv * w0.z, v0.w * inv * w0.w);
    op[512 + t * 2]     = packbf(v1.x * inv * w1.x, v1.y * inv * w1.y);
    op[512 + t * 2 + 1] = packbf(v1.z * inv * w1.z, v1.w * inv * w1.w);
}

// ---------------- fused: x += p0 + p1 ; h = rmsnorm(x) * w ----------------
__global__ void rmsadd2_kernel(float* __restrict__ x, const float* __restrict__ p0,
                               const float* __restrict__ p1, const float* __restrict__ w,
                               u16* __restrict__ o) {
    int row = blockIdx.x, t = threadIdx.x;
    long base = (long)row * 2048;
    float4 v0 = *reinterpret_cast<const float4*>(x + base + t * 4);
    float4 v1 = *reinterpret_cast<const float4*>(x + base + 1024 + t * 4);
    float4 a0 = *reinterpret_cast<const float4*>(p0 + base + t * 4);
    float4 a1 = *reinterpret_cast<const float4*>(p0 + base + 1024 + t * 4);
    float4 b0 = *reinterpret_cast<const float4*>(p1 + base + t * 4);
    float4 b1 = *reinterpret_cast<const float4*>(p1 + base + 1024 + t * 4);
    v0.x += a0.x + b0.x; v0.y += a0.y + b0.y; v0.z += a0.z + b0.z; v0.w += a0.w + b0.w;
    v1.x += a1.x + b1.x; v1.y += a1.y + b1.y; v1.z += a1.z + b1.z; v1.w += a1.w + b1.w;
    *reinterpret_cast<float4*>(x + base + t * 4) = v0;
    *reinterpret_cast<float4*>(x + base + 1024 + t * 4) = v1;
    float ss = v0.x * v0.x + v0.y * v0.y + v0.z * v0.z + v0.w * v0.w
             + v1.x * v1.x + v1.y * v1.y + v1.z * v1.z + v1.w * v1.w;
#pragma unroll
    for (int ofs = 32; ofs; ofs >>= 1) ss += __shfl_xor(ss, ofs);
    __shared__ float red[4];
    if ((t & 63) == 0) red[t >> 6] = ss;
    __syncthreads();
    ss = red[0] + red[1] + red[2] + red[3];
    float inv = 1.0f / sqrtf(ss * (1.0f / 2048.0f) + 1e-5f);
    float4 w0 = *reinterpret_cast<const float4*>(w + t * 4);
    float4 w1 = *reinterpret_cast<const float4*>(w + 1024 + t * 4);
    u32* op = (u32*)(o + (long)row * 2048);
    op[t * 2]           = packbf(v0.x * inv * w0.x, v0.y * inv * w0.y);
    op[t * 2 + 1]       = packbf(v0.z * inv * w0.z, v0.w * inv * w0.w);
    op[512 + t * 2]     = packbf(v1.x * inv * w1.x, v1.y * inv * w1.y);
    op[512 + t * 2 + 1] = packbf(v1.z * inv * w1.z, v1.w * inv * w1.w);
}

// ---------------- RoPE on q (bf16, in place in qkv, pos = 2048+s) ----------------
__global__ void rope_q_kernel(u16* __restrict__ qkv) {
    int idx = blockIdx.x * 256 + threadIdx.x;  // 1024*16*64
    int fi = idx & 63;
    int hh = (idx >> 6) & 15;
    int s = idx >> 10;
    u16* p = qkv + (long)s * 3072 + hh * 128 + fi;
    float q0 = bf2f(p[0]), q1 = bf2f(p[64]);
    float inv = exp2f((float)fi * -0.20762050593046014f);  // 10000^(-fi/64)
    float ang = (float)(2048 + s) * inv;
    float sn, cs;
    sincosf(ang, &sn, &cs);
    p[0]  = (u16)bf16_1(q0 * cs - q1 * sn);
    p[64] = (u16)bf16_1(q1 * cs + q0 * sn);
}

// ---------------- build K [16][3072][128] bf16 (cache + repeated new, RoPE) ----------------
__global__ void build_k_kernel(const float* __restrict__ kc, const u16* __restrict__ qkv,
                               u16* __restrict__ kf) {
    int t = blockIdx.x * 256 + threadIdx.x;
    int hh = blockIdx.y;
    int fi = t & 63;
    int j = t >> 6;
    float k0, k1;
    if (j < 2048) {
        const float* kp = kc + ((long)hh * 2048 + j) * 128;
        k0 = kp[fi]; k1 = kp[fi + 64];
    } else {
        int s = j - 2048;
        const u16* kp = qkv + (long)s * 3072 + 2048 + (hh >> 2) * 128;
        k0 = bf2f(kp[fi]); k1 = bf2f(kp[fi + 64]);
    }
    float inv = exp2f((float)fi * -0.20762050593046014f);
    float ang = (float)j * inv;
    float sn, cs;
    sincosf(ang, &sn, &cs);
    u16* kd = kf + ((long)hh * 3072 + j) * 128;
    kd[fi]      = (u16)bf16_1(k0 * cs - k1 * sn);
    kd[fi + 64] = (u16)bf16_1(k1 * cs + k0 * sn);
}

// ---------------- build V^T [16][128][3072] bf16 via LDS transpose ----------------
__global__ void build_vT_kernel(const float* __restrict__ vc, const u16* __restrict__ qkv,
                                u16* __restrict__ vfT) {
    __shared__ u16 tile[64][137];
    int hh = blockIdx.y, j0 = blockIdx.x * 64;
    int t = threadIdx.x;
    int d = t & 127, jr = t >> 7;
#pragma unroll
    for (int p = 0; p < 32; ++p) {
        int j = jr + p * 2;
        int gj = j0 + j;
        float v;
        if (gj < 2048) v = vc[((long)hh * 2048 + gj) * 128 + d];
        else           v = bf2f(qkv[(long)(gj - 2048) * 3072 + 2560 + (hh >> 2) * 128 + d]);
        tile[j][d] = (u16)bf16_1(v);
    }
    __syncthreads();
    int jp = t & 31, dd = t >> 5;
#pragma unroll
    for (int p = 0; p < 16; ++p) {
        int d2 = dd + p * 8;
        u32 w = (u32)tile[jp * 2][d2] | ((u32)tile[jp * 2 + 1][d2] << 16);
        ((u32*)vfT)[((long)hh * 128 + d2) * 1536 + (j0 >> 1) + jp] = w;
    }
}

// ---------------- SiLU(gate)*up on merged [1024][11264] buffer, in place into gate ------
__global__ void silu_mul_kernel(u32* __restrict__ gu) {
    int p = blockIdx.x * 256 + threadIdx.x;   // 0..2815
    int r = blockIdx.y;
    u32* rowp = gu + (long)r * 5632;
    u32 gv = rowp[p], uv = rowp[2816 + p];
    float g0 = bf2f((u16)(gv & 0xffff)), g1 = bf2f((u16)(gv >> 16));
    float u0 = bf2f((u16)(uv & 0xffff)), u1 = bf2f((u16)(uv >> 16));
    float r0 = (g0 / (1.0f + __expf(-g0))) * u0;
    float r1 = (g1 / (1.0f + __expf(-g1))) * u1;
    rowp[p] = packbf(r0, r1);
}

// ---------------- host ----------------
extern "C" void kernel_launch(void* const* d_in, const int* in_sizes, int n_in,
                              void* d_out, int out_size, void* d_ws, size_t ws_size,
                              hipStream_t stream) {
    const int*   ids   = (const int*)d_in[0];
    const float* kv    = (const float*)d_in[1];
    const float* emb   = (const float*)d_in[2];
    const float* Wq    = (const float*)d_in[3];
    const float* Wk    = (const float*)d_in[4];
    const float* Wv    = (const float*)d_in[5];
    const float* Wo    = (const float*)d_in[6];
    const float* ln1   = (const float*)d_in[7];
    const float* ln2   = (const float*)d_in[8];
    const float* Wg    = (const float*)d_in[9];
    const float* Wu    = (const float*)d_in[10];
    const float* Wd    = (const float*)d_in[11];
    const float* normw = (const float*)d_in[12];
    const float* lmh   = (const float*)d_in[13];
    float* out = (float*)d_out;
    (void)in_sizes; (void)n_in; (void)out_size; (void)ws_size;

    char* w = (char*)d_ws;
    u16*   wt     = (u16*)w;                      // per-layer bf16^T weights (90.2 MB)
    float* x      = (float*)(w + 90177536);       // [1024,2048] fp32 residual
    u16*   h      = (u16*)(w + 98566144);         // [1024,2048] bf16
    u16*   qkv    = (u16*)(w + 102760448);        // [1024,3072] bf16 (layers only)
    u16*   kf     = (u16*)(w + 109051904);        // [16,3072,128] bf16
    u16*   vfT    = (u16*)(w + 121634816);        // [16,128,3072] bf16
    float* partWo = (float*)(w + 134217728);      // 2x[1024,2048] fp32
    u16*   gu     = (u16*)(w + 134217728);        // [1024,11264] bf16 (after Wo reduce)
    float* partWd = (float*)(w + 157286400);      // 2x[1024,2048] fp32
    u16*   attn   = (u16*)(w + 174063616);        // [1024,2048] bf16 (separate: flash reads qkv!)
    u16*   lmT    = (u16*)(w + 102760448);        // [32000][2048] bf16 post-layers (131 MB)

    u16* qkvT = wt;                 // [3072][2048]
    u16* WoT  = wt + 6291456;       // [2048][2048]
    u16* guT  = wt + 10485760;      // [11264][2048]
    u16* WdT  = wt + 33554432;      // [2048][5632]

    embed_kernel<<<2048, 256, 0, stream>>>(ids, emb, x);
    rmsnorm_kernel<<<1024, 256, 0, stream>>>(x, ln1, h);

    for (int l = 0; l < 2; ++l) {
        const float* Wq_l = Wq + (long)l * 2048 * 2048;
        const float* Wk_l = Wk + (long)l * 2048 * 512;
        const float* Wv_l = Wv + (long)l * 2048 * 512;
        const float* Wo_l = Wo + (long)l * 2048 * 2048;
        const float* Wg_l = Wg + (long)l * 2048 * 5632;
        const float* Wu_l = Wu + (long)l * 2048 * 5632;
        const float* Wd_l = Wd + (long)l * 5632 * 2048;
        const float* kc = kv + (long)l * 16 * 2048 * 128;
        const float* vc = kv + (long)(2 + l) * 16 * 2048 * 128;

        convT_kernel<<<dim3(32, 32), 256, 0, stream>>>(Wq_l, 2048, 0, qkvT, 2048);
        convT_kernel<<<dim3(8, 32),  256, 0, stream>>>(Wk_l, 512,  0, qkvT + 2048 * 2048, 2048);
        convT_kernel<<<dim3(8, 32),  256, 0, stream>>>(Wv_l, 512,  0, qkvT + 2560 * 2048, 2048);
        convT_kernel<<<dim3(32, 32), 256, 0, stream>>>(Wo_l, 2048, 0, WoT, 2048);
        convT_kernel<<<dim3(88, 32), 256, 0, stream>>>(Wg_l, 5632, 0, guT, 2048);
        convT_kernel<<<dim3(88, 32), 256, 0, stream>>>(Wu_l, 5632, 0, guT + 5632 * 2048, 2048);
        convT_kernel<<<dim3(32, 88), 256, 0, stream>>>(Wd_l, 2048, 0, WdT, 5632);

        // fused QKV projection: [1024,3072]
        bgemm_kernel<u16><<<dim3(8, 24, 1), 256, 0, stream>>>(
            h, 2048, 0, qkvT, 2048, 0, qkv, 3072, 0, 2048);
        rope_q_kernel<<<4096, 256, 0, stream>>>(qkv);
        build_k_kernel<<<dim3(768, 16), 256, 0, stream>>>(kc, qkv, kf);
        build_vT_kernel<<<dim3(48, 16), 256, 0, stream>>>(vc, qkv, vfT);

        // fused attention (scores+mask+softmax+PV)
        flash_kernel<<<dim3(32, 16), 128, 0, stream>>>(qkv, kf, vfT, attn);

        // Wo with split-K, partials then fused add+rmsnorm(ln2)
        bgemm_kernel<float><<<dim3(8, 16, 2), 256, 0, stream>>>(
            attn, 2048, 1024, WoT, 2048, 1024,
            partWo, 2048, (long)1024 * 2048, 1024);
        rmsadd2_kernel<<<1024, 256, 0, stream>>>(x, partWo, partWo + 2097152, ln2 + l * 2048, h);

        // fused gate+up: [1024,11264]
        bgemm_kernel<u16><<<dim3(8, 88, 1), 256, 0, stream>>>(
            h, 2048, 0, guT, 2048, 0, gu, 11264, 0, 2048);
        silu_mul_kernel<<<dim3(11, 1024), 256, 0, stream>>>((u32*)gu);

        // Wd with split-K, partials then fused add+rmsnorm(next norm weight)
        bgemm_kernel<float><<<dim3(8, 16, 2), 256, 0, stream>>>(
            gu, 11264, 2816, WdT, 5632, 2816,
            partWd, 2048, (long)1024 * 2048, 2816);
        rmsadd2_kernel<<<1024, 256, 0, stream>>>(
            x, partWd, partWd + 2097152, (l == 0) ? (ln1 + 2048) : normw, h);
    }

    // lm_head: single conversion + single GEMM (grid 8x250 = 2000 blocks, XCD-swizzled)
    convT_kernel<<<dim3(500, 32), 256, 0, stream>>>(lmh, 32000, 0, lmT, 2048);
    bgemm_kernel<float><<<dim3(8, 250, 1), 256, 0, stream>>>(
        h, 2048, 0, lmT, 2048, 0, out, 32000, 0, 2048);
}

// Round 6
// 991.224 us; speedup vs baseline: 8.1314x; 1.0343x over previous
//
#include <hip/hip_runtime.h>
#include <hip/hip_bf16.h>
#include <stdint.h>

typedef __attribute__((ext_vector_type(8))) short bf16x8;
typedef __attribute__((ext_vector_type(4))) float f32x4;
typedef unsigned int u32;
typedef unsigned short u16;

// ---------------- helpers ----------------
__device__ __forceinline__ u32 bf16_1(float x) {
    u32 u = __float_as_uint(x);
    return (u + 0x7fffu + ((u >> 16) & 1u)) >> 16;   // RNE to bf16
}
__device__ __forceinline__ u32 packbf(float a, float b) {
    return bf16_1(a) | (bf16_1(b) << 16);
}
__device__ __forceinline__ float bf2f(u16 v) {
    return __uint_as_float(((u32)v) << 16);
}
// XOR-swizzle involution for 128-elem (16-chunk) bf16 rows; same map on write & read.
__device__ __forceinline__ int swz16(int row, int chunk) {
    return (chunk & 8) | ((chunk ^ row) & 7);
}

typedef const __attribute__((address_space(1))) u32* gptr_t;
typedef __attribute__((address_space(3))) u32* lptr_t;
__device__ __forceinline__ void gload16(const u16* g, u16* l) {
    __builtin_amdgcn_global_load_lds((gptr_t)g, (lptr_t)l, 16, 0, 0);
}

// ============ bf16 GEMM: C[M,N] = A[M,K] @ B^T[N,K] ============
// 128x128 tile, BK=64, global_load_lds staging, XOR-swizzled LDS (proven r2-r4).
// XCD panel swizzle (T1): lin = xcd*(nwg/8)+pos decoded in (4-m-panel, n, m) order.
template<typename OUT>
__global__ __launch_bounds__(256) void bgemm_kernel(
    const u16* __restrict__ A, int lda, long zA,
    const u16* __restrict__ B, int ldb, long zB,
    OUT* __restrict__ C, int ldc, long zC,
    int K)
{
    __shared__ __align__(16) u16 As[128 * 64];
    __shared__ __align__(16) u16 Bs[128 * 64];
    const int z = blockIdx.z;
    A += (long)z * zA;
    B += (long)z * zB;
    C += (long)z * zC;

    const int gx = gridDim.x, gy = gridDim.y;
    int tm, tn;
    if (gx == 8) {                       // all our 128-GEMM grids: bijective (nwg%8==0)
        int id = blockIdx.y * gx + blockIdx.x;
        int nwg8 = (gx * gy) >> 3;
        int lin = (id & 7) * nwg8 + (id >> 3);
        int span = gy << 2;              // gy * PM (PM=4)
        int pp = lin / span;
        int rem = lin - pp * span;
        tn = rem >> 2;
        tm = (pp << 2) + (rem & 3);
    } else { tm = blockIdx.x; tn = blockIdx.y; }
    const int m0 = tm * 128, n0 = tn * 128;

    const int tid = threadIdx.x;
    const int lane = tid & 63, wave = tid >> 6;
    const int wm = wave & 1, wn = wave >> 1;
    const int rl = lane & 15, gg = lane >> 4;
    const int srow = lane >> 3, schunk = lane & 7;

    f32x4 zero4 = {0.f, 0.f, 0.f, 0.f};
    f32x4 acc[4][4];
#pragma unroll
    for (int i = 0; i < 4; ++i)
#pragma unroll
        for (int j = 0; j < 4; ++j) acc[i][j] = zero4;

    for (int k0 = 0; k0 < K; k0 += 64) {
#pragma unroll
        for (int it = 0; it < 4; ++it) {
            int ii = wave * 4 + it;
            int row = ii * 8 + srow;
            int sc_ = (schunk ^ (row & 7)) << 3;
            gload16(A + (long)(m0 + row) * lda + k0 + sc_, &As[ii * 512]);
            gload16(B + (long)(n0 + row) * ldb + k0 + sc_, &Bs[ii * 512]);
        }
        __syncthreads();
#pragma unroll
        for (int kk = 0; kk < 2; ++kk) {
            bf16x8 af[4], bq[4];
#pragma unroll
            for (int mf = 0; mf < 4; ++mf) {
                int row = wm * 64 + mf * 16 + rl;
                af[mf] = *reinterpret_cast<const bf16x8*>(&As[row * 64 + (((kk * 4 + gg) ^ (row & 7)) << 3)]);
            }
#pragma unroll
            for (int nf = 0; nf < 4; ++nf) {
                int row = wn * 64 + nf * 16 + rl;
                bq[nf] = *reinterpret_cast<const bf16x8*>(&Bs[row * 64 + (((kk * 4 + gg) ^ (row & 7)) << 3)]);
            }
#pragma unroll
            for (int mf = 0; mf < 4; ++mf)
#pragma unroll
                for (int nf = 0; nf < 4; ++nf)
                    acc[mf][nf] = __builtin_amdgcn_mfma_f32_16x16x32_bf16(af[mf], bq[nf], acc[mf][nf], 0, 0, 0);
        }
        __syncthreads();
    }
#pragma unroll
    for (int mf = 0; mf < 4; ++mf) {
#pragma unroll
        for (int nf = 0; nf < 4; ++nf) {
            int col = n0 + wn * 64 + nf * 16 + rl;
#pragma unroll
            for (int r = 0; r < 4; ++r) {
                int row = m0 + wm * 64 + mf * 16 + gg * 4 + r;
                long idx = (long)row * ldc + col;
                float v = acc[mf][nf][r];
                if constexpr (sizeof(OUT) == 2) ((u16*)C)[idx] = (u16)bf16_1(v);
                else C[idx] = v;
            }
        }
    }
}

// ============ 256x256 BK=64 pipelined GEMM (T2+T3+T4+T5) ============
// 512 threads = 8 waves (2M x 4N), per-wave 128x64 out, acc[8][4].
// LDS: 2 x (A 32KB + B 32KB) = 128 KB double buffer.
// Counted vmcnt(8): tile t+1's 8 loads stay in flight across barriers.
// Prefetch t+2 issued after post-compute barrier of t (no LDS write/read race).
template<typename OUT>
__global__ __launch_bounds__(512) void bgemm256_kernel(
    const u16* __restrict__ A, int lda,
    const u16* __restrict__ B, int ldb,
    OUT* __restrict__ C, int ldc,
    int K)
{
    __shared__ __align__(16) u16 lds[65536];    // [2][ A 16384 | B 16384 ]
    // m204 bijective XCD swizzle, decode n-major (panel = all 4 m-tiles)
    const int nwg = gridDim.x * gridDim.y;
    const int id = blockIdx.y * gridDim.x + blockIdx.x;
    const int xcd = id & 7, pos = id >> 3;
    const int q = nwg >> 3, r = nwg & 7;
    const int lin = (xcd < r ? xcd * (q + 1) : r * (q + 1) + (xcd - r) * q) + pos;
    const int tm = lin & 3, tn = lin >> 2;
    const int m0 = tm * 256, n0 = tn * 256;

    const int tid = threadIdx.x;
    const int lane = tid & 63, wave = tid >> 6;
    const int wm = wave >> 2, wn = wave & 3;          // 2M x 4N
    const int rl = lane & 15, gg = lane >> 4;
    const int srow = lane >> 3, schunk = lane & 7;
    const int NT = K >> 6;

    f32x4 acc[8][4];
#pragma unroll
    for (int i = 0; i < 8; ++i)
#pragma unroll
        for (int j = 0; j < 4; ++j) acc[i][j] = (f32x4){0.f, 0.f, 0.f, 0.f};

    const u16* Abase = A + (long)m0 * lda;
    const u16* Bbase = B + (long)n0 * ldb;

    // stage tile t into buffer buf: 8 gloads/wave (4 A + 4 B)
    auto stage = [&](int t, int buf) {
        u16* Al = lds + buf * 32768;
        u16* Bl = Al + 16384;
        const u16* Ak = Abase + t * 64;
        const u16* Bk = Bbase + t * 64;
#pragma unroll
        for (int it = 0; it < 4; ++it) {
            int ii = wave * 4 + it;                  // 0..31, 8 rows each
            int row = ii * 8 + srow;
            int sc_ = (schunk ^ (row & 7)) << 3;
            gload16(Ak + (long)row * lda + sc_, Al + ii * 512);
            gload16(Bk + (long)row * ldb + sc_, Bl + ii * 512);
        }
    };

    stage(0, 0);
    stage(1, 1);

    for (int t = 0; t < NT; ++t) {
        if (t < NT - 1) { asm volatile("s_waitcnt vmcnt(8)" ::: "memory"); }
        else           { asm volatile("s_waitcnt vmcnt(0)" ::: "memory"); }
        __builtin_amdgcn_s_barrier();      // all waves' tile-t loads landed
        const u16* Al = lds + (t & 1) * 32768;
        const u16* Bl = Al + 16384;
#pragma unroll
        for (int kk = 0; kk < 2; ++kk) {
            bf16x8 af[8], bq[4];
#pragma unroll
            for (int mf = 0; mf < 8; ++mf) {
                int row = wm * 128 + mf * 16 + rl;
                af[mf] = *reinterpret_cast<const bf16x8*>(&Al[row * 64 + (((kk * 4 + gg) ^ (row & 7)) << 3)]);
            }
#pragma unroll
            for (int nf = 0; nf < 4; ++nf) {
                int row = wn * 64 + nf * 16 + rl;
                bq[nf] = *reinterpret_cast<const bf16x8*>(&Bl[row * 64 + (((kk * 4 + gg) ^ (row & 7)) << 3)]);
            }
            __builtin_amdgcn_s_setprio(1);
#pragma unroll
            for (int mf = 0; mf < 8; ++mf)
#pragma unroll
                for (int nf = 0; nf < 4; ++nf)
                    acc[mf][nf] = __builtin_amdgcn_mfma_f32_16x16x32_bf16(af[mf], bq[nf], acc[mf][nf], 0, 0, 0);
            __builtin_amdgcn_s_setprio(0);
            __builtin_amdgcn_sched_barrier(0);
        }
        __builtin_amdgcn_s_barrier();      // all reads of buf[t&1] complete
        if (t + 2 < NT) stage(t + 2, t & 1);
    }

#pragma unroll
    for (int mf = 0; mf < 8; ++mf) {
#pragma unroll
        for (int nf = 0; nf < 4; ++nf) {
            int col = n0 + wn * 64 + nf * 16 + rl;
#pragma unroll
            for (int r = 0; r < 4; ++r) {
                int row = m0 + wm * 128 + mf * 16 + gg * 4 + r;
                long idx = (long)row * ldc + col;
                float v = acc[mf][nf][r];
                if constexpr (sizeof(OUT) == 2) ((u16*)C)[idx] = (u16)bf16_1(v);
                else C[idx] = v;
            }
        }
    }
}

// ============ flash attention: S^T=K·Q^T, online softmax, O^T=V^T·P^T ============
__global__ __launch_bounds__(128) void flash_kernel(
    const u16* __restrict__ qkv, const u16* __restrict__ kf,
    const u16* __restrict__ vfT, u16* __restrict__ attn)
{
    __shared__ __align__(16) u16 Ks[128 * 128];
    __shared__ __align__(16) u16 Vs[128 * 128];
    __shared__ __align__(16) u16 Ps[32 * 128];
    // XCD swizzle: 512 blocks -> xcd owns lin [xcd*64, xcd*64+64) = 2 heads
    const int id = blockIdx.y * gridDim.x + blockIdx.x;
    const int lin = (id & 7) * 64 + (id >> 3);
    const int h = lin >> 5;
    const int q0 = (lin & 31) * 32;
    const int t = threadIdx.x;
    const int lane = t & 63, w = t >> 6;
    const int rl = lane & 15, gg = lane >> 4;
    const int qg = q0 + w * 16 + rl;
    const int qrow = w * 16 + rl;
    const int srow = t >> 4, schunk = t & 15;

    bf16x8 qf[4];
#pragma unroll
    for (int kk = 0; kk < 4; ++kk)
        qf[kk] = *reinterpret_cast<const bf16x8*>(qkv + (long)qg * 3072 + h * 128 + kk * 32 + gg * 8);

    f32x4 o[8];
#pragma unroll
    for (int i = 0; i < 8; ++i) o[i] = (f32x4){0.f, 0.f, 0.f, 0.f};
    float m = -INFINITY, l = 0.f;

    const int cs = q0 & ~511;
    const int ntiles = 16 + ((q0 - cs + 159) >> 7);

    for (int tt = 0; tt < ntiles; ++tt) {
        const int tb = (tt < 16) ? tt * 128 : (2048 + cs + (tt - 16) * 128);
#pragma unroll
        for (int i = 0; i < 16; ++i) {
            int row = i * 8 + srow;
            int cw = swz16(row, schunk) * 8;
            gload16(kf + ((long)(h * 3072 + tb + row)) * 128 + cw, &Ks[i * 1024 + w * 512]);
        }
#pragma unroll
        for (int i = 0; i < 16; ++i) {
            int row = i * 8 + srow;
            int cw = swz16(row, schunk) * 8;
            gload16(vfT + ((long)(h * 128 + row)) * 3072 + tb + cw, &Vs[i * 1024 + w * 512]);
        }
        __syncthreads();
        f32x4 s[8];
#pragma unroll
        for (int f = 0; f < 8; ++f) s[f] = (f32x4){0.f, 0.f, 0.f, 0.f};
#pragma unroll
        for (int kk = 0; kk < 4; ++kk) {
#pragma unroll
            for (int f = 0; f < 8; ++f) {
                int row = f * 16 + rl;
                bf16x8 kfrag = *reinterpret_cast<const bf16x8*>(
                    &Ks[row * 128 + swz16(row, kk * 4 + gg) * 8]);
                s[f] = __builtin_amdgcn_mfma_f32_16x16x32_bf16(kfrag, qf[kk], s[f], 0, 0, 0);
            }
        }
        float tm = -INFINITY;
#pragma unroll
        for (int f = 0; f < 8; ++f) {
#pragma unroll
            for (int r = 0; r < 4; ++r) {
                float v = s[f][r] * 0.08838834764831845f;
                if (tt >= 16) {
                    int jloc = (tb - 2048) + f * 16 + gg * 4 + r;
                    if (jloc > qg) v = -INFINITY;
                }
                s[f][r] = v;
                tm = fmaxf(tm, v);
            }
        }
        tm = fmaxf(tm, __shfl_xor(tm, 16));
        tm = fmaxf(tm, __shfl_xor(tm, 32));
        float mnew = fmaxf(m, tm);
        float alpha = __expf(m - mnew);
        m = mnew;
        float ts = 0.f;
#pragma unroll
        for (int f = 0; f < 8; ++f) {
#pragma unroll
            for (int r = 0; r < 4; ++r) {
                float e = __expf(s[f][r] - m);
                s[f][r] = e;
                ts += e;
            }
        }
        ts += __shfl_xor(ts, 16);
        ts += __shfl_xor(ts, 32);
        l = l * alpha + ts;
#pragma unroll
        for (int i = 0; i < 8; ++i)
#pragma unroll
            for (int r = 0; r < 4; ++r) o[i][r] *= alpha;
#pragma unroll
        for (int f = 0; f < 8; ++f) {
            int kvb = f * 16 + gg * 4;
            u32* dst = (u32*)&Ps[qrow * 128 + swz16(qrow, kvb >> 3) * 8 + (kvb & 7)];
            dst[0] = packbf(s[f][0], s[f][1]);
            dst[1] = packbf(s[f][2], s[f][3]);
        }
#pragma unroll
        for (int kk = 0; kk < 4; ++kk) {
            bf16x8 pfrag = *reinterpret_cast<const bf16x8*>(
                &Ps[qrow * 128 + swz16(qrow, kk * 4 + gg) * 8]);
#pragma unroll
            for (int fd = 0; fd < 8; ++fd) {
                int row = fd * 16 + rl;
                bf16x8 vfrag = *reinterpret_cast<const bf16x8*>(
                    &Vs[row * 128 + swz16(row, kk * 4 + gg) * 8]);
                o[fd] = __builtin_amdgcn_mfma_f32_16x16x32_bf16(vfrag, pfrag, o[fd], 0, 0, 0);
            }
        }
        __syncthreads();
    }
    float inv = 1.0f / l;
    u32* orow = (u32*)(attn + (long)qg * 2048 + h * 128);
#pragma unroll
    for (int fd = 0; fd < 8; ++fd) {
        int d0 = fd * 16 + gg * 4;
        orow[d0 >> 1]       = packbf(o[fd][0] * inv, o[fd][1] * inv);
        orow[(d0 >> 1) + 1] = packbf(o[fd][2] * inv, o[fd][3] * inv);
    }
}

// ============ transpose-convert: W[K,N] fp32 -> WT[N,K] bf16 ============
__global__ void convT_kernel(const float* __restrict__ W, int ldw, int n0,
                             u16* __restrict__ WT, int ldk) {
    __shared__ float tile[64][65];
    int t = threadIdx.x;
    int c = t & 63, r4 = t >> 6;
    const float* src = W + (long)(blockIdx.y * 64 + r4) * ldw + n0 + blockIdx.x * 64 + c;
#pragma unroll
    for (int p = 0; p < 16; ++p)
        tile[r4 + p * 4][c] = src[(long)p * 4 * ldw];
    __syncthreads();
    int kp = t & 31, cc = t >> 5;
#pragma unroll
    for (int p = 0; p < 8; ++p) {
        int crow = cc + p * 8;
        float a = tile[kp * 2][crow], b = tile[kp * 2 + 1][crow];
        ((u32*)WT)[(((long)(blockIdx.x * 64 + crow) * ldk + blockIdx.y * 64) >> 1) + kp] = packbf(a, b);
    }
}

// ---------------- embedding gather ----------------
__global__ void embed_kernel(const int* __restrict__ ids, const float* __restrict__ emb,
                             float* __restrict__ x) {
    int idx = blockIdx.x * 256 + threadIdx.x;
    int s = idx >> 9, c = idx & 511;
    float4 v = *reinterpret_cast<const float4*>(emb + (long)ids[s] * 2048 + c * 4);
    *reinterpret_cast<float4*>(x + (long)s * 2048 + c * 4) = v;
}

// ---------------- RMSNorm: fp32 in -> bf16 out ----------------
__global__ void rmsnorm_kernel(const float* __restrict__ x, const float* __restrict__ w,
                               u16* __restrict__ o) {
    int row = blockIdx.x, t = threadIdx.x;
    const float* xr = x + (long)row * 2048;
    float4 v0 = *reinterpret_cast<const float4*>(xr + t * 4);
    float4 v1 = *reinterpret_cast<const float4*>(xr + 1024 + t * 4);
    float ss = v0.x * v0.x + v0.y * v0.y + v0.z * v0.z + v0.w * v0.w
             + v1.x * v1.x + v1.y * v1.y + v1.z * v1.z + v1.w * v1.w;
#pragma unroll
    for (int ofs = 32; ofs; ofs >>= 1) ss += __shfl_xor(ss, ofs);
    __shared__ float red[4];
    if ((t & 63) == 0) red[t >> 6] = ss;
    __syncthreads();
    ss = red[0] + red[1] + red[2] + red[3];
    float inv = 1.0f / sqrtf(ss * (1.0f / 2048.0f) + 1e-5f);
    float4 w0 = *reinterpret_cast<const float4*>(w + t * 4);
    float4 w1 = *reinterpret_cast<const float4*>(w + 1024 + t * 4);
    u32* op = (u32*)(o + (long)row * 2048);
    op[t * 2]           = packbf(v0.x * inv * w0.x, v0.y * inv * w0.y);
    op[t * 2 + 1]       = packbf(v0.z * inv * w0.z, v0.w * inv * w0.w);
    op[512 + t * 2]     = packbf(v1.x * inv * w1.x, v1.y * inv * w1.y);
    op[512 + t * 2 + 1] = packbf(v1.z * inv * w1.z, v1.w * inv * w1.w);
}

// ---------------- fused: x += p0 + p1 ; h = rmsnorm(x) * w ----------------
__global__ void rmsadd2_kernel(float* __restrict__ x, const float* __restrict__ p0,
                               const float* __restrict__ p1, const float* __restrict__ w,
                               u16* __restrict__ o) {
    int row = blockIdx.x, t = threadIdx.x;
    long base = (long)row * 2048;
    float4 v0 = *reinterpret_cast<const float4*>(x + base + t * 4);
    float4 v1 = *reinterpret_cast<const float4*>(x + base + 1024 + t * 4);
    float4 a0 = *reinterpret_cast<const float4*>(p0 + base + t * 4);
    float4 a1 = *reinterpret_cast<const float4*>(p0 + base + 1024 + t * 4);
    float4 b0 = *reinterpret_cast<const float4*>(p1 + base + t * 4);
    float4 b1 = *reinterpret_cast<const float4*>(p1 + base + 1024 + t * 4);
    v0.x += a0.x + b0.x; v0.y += a0.y + b0.y; v0.z += a0.z + b0.z; v0.w += a0.w + b0.w;
    v1.x += a1.x + b1.x; v1.y += a1.y + b1.y; v1.z += a1.z + b1.z; v1.w += a1.w + b1.w;
    *reinterpret_cast<float4*>(x + base + t * 4) = v0;
    *reinterpret_cast<float4*>(x + base + 1024 + t * 4) = v1;
    float ss = v0.x * v0.x + v0.y * v0.y + v0.z * v0.z + v0.w * v0.w
             + v1.x * v1.x + v1.y * v1.y + v1.z * v1.z + v1.w * v1.w;
#pragma unroll
    for (int ofs = 32; ofs; ofs >>= 1) ss += __shfl_xor(ss, ofs);
    __shared__ float red[4];
    if ((t & 63) == 0) red[t >> 6] = ss;
    __syncthreads();
    ss = red[0] + red[1] + red[2] + red[3];
    float inv = 1.0f / sqrtf(ss * (1.0f / 2048.0f) + 1e-5f);
    float4 w0 = *reinterpret_cast<const float4*>(w + t * 4);
    float4 w1 = *reinterpret_cast<const float4*>(w + 1024 + t * 4);
    u32* op = (u32*)(o + (long)row * 2048);
    op[t * 2]           = packbf(v0.x * inv * w0.x, v0.y * inv * w0.y);
    op[t * 2 + 1]       = packbf(v0.z * inv * w0.z, v0.w * inv * w0.w);
    op[512 + t * 2]     = packbf(v1.x * inv * w1.x, v1.y * inv * w1.y);
    op[512 + t * 2 + 1] = packbf(v1.z * inv * w1.z, v1.w * inv * w1.w);
}

// ---------------- RoPE on q (bf16, in place in qkv, pos = 2048+s) ----------------
__global__ void rope_q_kernel(u16* __restrict__ qkv) {
    int idx = blockIdx.x * 256 + threadIdx.x;
    int fi = idx & 63;
    int hh = (idx >> 6) & 15;
    int s = idx >> 10;
    u16* p = qkv + (long)s * 3072 + hh * 128 + fi;
    float q0 = bf2f(p[0]), q1 = bf2f(p[64]);
    float inv = exp2f((float)fi * -0.20762050593046014f);
    float ang = (float)(2048 + s) * inv;
    float sn, cs;
    sincosf(ang, &sn, &cs);
    p[0]  = (u16)bf16_1(q0 * cs - q1 * sn);
    p[64] = (u16)bf16_1(q1 * cs + q0 * sn);
}

// ---------------- build K [16][3072][128] bf16 (cache + repeated new, RoPE) ----------------
__global__ void build_k_kernel(const float* __restrict__ kc, const u16* __restrict__ qkv,
                               u16* __restrict__ kf) {
    int t = blockIdx.x * 256 + threadIdx.x;
    int hh = blockIdx.y;
    int fi = t & 63;
    int j = t >> 6;
    float k0, k1;
    if (j < 2048) {
        const float* kp = kc + ((long)hh * 2048 + j) * 128;
        k0 = kp[fi]; k1 = kp[fi + 64];
    } else {
        int s = j - 2048;
        const u16* kp = qkv + (long)s * 3072 + 2048 + (hh >> 2) * 128;
        k0 = bf2f(kp[fi]); k1 = bf2f(kp[fi + 64]);
    }
    float inv = exp2f((float)fi * -0.20762050593046014f);
    float ang = (float)j * inv;
    float sn, cs;
    sincosf(ang, &sn, &cs);
    u16* kd = kf + ((long)hh * 3072 + j) * 128;
    kd[fi]      = (u16)bf16_1(k0 * cs - k1 * sn);
    kd[fi + 64] = (u16)bf16_1(k1 * cs + k0 * sn);
}

// ---------------- build V^T [16][128][3072] bf16 via LDS transpose ----------------
__global__ void build_vT_kernel(const float* __restrict__ vc, const u16* __restrict__ qkv,
                                u16* __restrict__ vfT) {
    __shared__ u16 tile[64][137];
    int hh = blockIdx.y, j0 = blockIdx.x * 64;
    int t = threadIdx.x;
    int d = t & 127, jr = t >> 7;
#pragma unroll
    for (int p = 0; p < 32; ++p) {
        int j = jr + p * 2;
        int gj = j0 + j;
        float v;
        if (gj < 2048) v = vc[((long)hh * 2048 + gj) * 128 + d];
        else           v = bf2f(qkv[(long)(gj - 2048) * 3072 + 2560 + (hh >> 2) * 128 + d]);
        tile[j][d] = (u16)bf16_1(v);
    }
    __syncthreads();
    int jp = t & 31, dd = t >> 5;
#pragma unroll
    for (int p = 0; p < 16; ++p) {
        int d2 = dd + p * 8;
        u32 w = (u32)tile[jp * 2][d2] | ((u32)tile[jp * 2 + 1][d2] << 16);
        ((u32*)vfT)[((long)hh * 128 + d2) * 1536 + (j0 >> 1) + jp] = w;
    }
}

// ---------------- SiLU(gate)*up on merged [1024][11264] buffer, in place into gate ------
__global__ void silu_mul_kernel(u32* __restrict__ gu) {
    int p = blockIdx.x * 256 + threadIdx.x;
    int r = blockIdx.y;
    u32* rowp = gu + (long)r * 5632;
    u32 gv = rowp[p], uv = rowp[2816 + p];
    float g0 = bf2f((u16)(gv & 0xffff)), g1 = bf2f((u16)(gv >> 16));
    float u0 = bf2f((u16)(uv & 0xffff)), u1 = bf2f((u16)(uv >> 16));
    float r0 = (g0 / (1.0f + __expf(-g0))) * u0;
    float r1 = (g1 / (1.0f + __expf(-g1))) * u1;
    rowp[p] = packbf(r0, r1);
}

// ---------------- host ----------------
extern "C" void kernel_launch(void* const* d_in, const int* in_sizes, int n_in,
                              void* d_out, int out_size, void* d_ws, size_t ws_size,
                              hipStream_t stream) {
    const int*   ids   = (const int*)d_in[0];
    const float* kv    = (const float*)d_in[1];
    const float* emb   = (const float*)d_in[2];
    const float* Wq    = (const float*)d_in[3];
    const float* Wk    = (const float*)d_in[4];
    const float* Wv    = (const float*)d_in[5];
    const float* Wo    = (const float*)d_in[6];
    const float* ln1   = (const float*)d_in[7];
    const float* ln2   = (const float*)d_in[8];
    const float* Wg    = (const float*)d_in[9];
    const float* Wu    = (const float*)d_in[10];
    const float* Wd    = (const float*)d_in[11];
    const float* normw = (const float*)d_in[12];
    const float* lmh   = (const float*)d_in[13];
    float* out = (float*)d_out;
    (void)in_sizes; (void)n_in; (void)out_size; (void)ws_size;

    char* w = (char*)d_ws;
    u16*   wt     = (u16*)w;                      // per-layer bf16^T weights (90.2 MB)
    float* x      = (float*)(w + 90177536);       // [1024,2048] fp32 residual
    u16*   h      = (u16*)(w + 98566144);         // [1024,2048] bf16
    u16*   qkv    = (u16*)(w + 102760448);        // [1024,3072] bf16 (layers only)
    u16*   kf     = (u16*)(w + 109051904);        // [16,3072,128] bf16
    u16*   vfT    = (u16*)(w + 121634816);        // [16,128,3072] bf16
    float* partWo = (float*)(w + 134217728);      // 2x[1024,2048] fp32
    u16*   gu     = (u16*)(w + 134217728);        // [1024,11264] bf16 (after Wo reduce)
    float* partWd = (float*)(w + 157286400);      // 2x[1024,2048] fp32
    u16*   attn   = (u16*)(w + 174063616);        // [1024,2048] bf16 (separate: flash reads qkv!)
    u16*   lmT    = (u16*)(w + 102760448);        // [32000][2048] bf16 post-layers (131 MB)

    u16* qkvT = wt;                 // [3072][2048]
    u16* WoT  = wt + 6291456;       // [2048][2048]
    u16* guT  = wt + 10485760;      // [11264][2048]
    u16* WdT  = wt + 33554432;      // [2048][5632]

    embed_kernel<<<2048, 256, 0, stream>>>(ids, emb, x);
    rmsnorm_kernel<<<1024, 256, 0, stream>>>(x, ln1, h);

    for (int l = 0; l < 2; ++l) {
        const float* Wq_l = Wq + (long)l * 2048 * 2048;
        const float* Wk_l = Wk + (long)l * 2048 * 512;
        const float* Wv_l = Wv + (long)l * 2048 * 512;
        const float* Wo_l = Wo + (long)l * 2048 * 2048;
        const float* Wg_l = Wg + (long)l * 2048 * 5632;
        const float* Wu_l = Wu + (long)l * 2048 * 5632;
        const float* Wd_l = Wd + (long)l * 5632 * 2048;
        const float* kc = kv + (long)l * 16 * 2048 * 128;
        const float* vc = kv + (long)(2 + l) * 16 * 2048 * 128;

        convT_kernel<<<dim3(32, 32), 256, 0, stream>>>(Wq_l, 2048, 0, qkvT, 2048);
        convT_kernel<<<dim3(8, 32),  256, 0, stream>>>(Wk_l, 512,  0, qkvT + 2048 * 2048, 2048);
        convT_kernel<<<dim3(8, 32),  256, 0, stream>>>(Wv_l, 512,  0, qkvT + 2560 * 2048, 2048);
        convT_kernel<<<dim3(32, 32), 256, 0, stream>>>(Wo_l, 2048, 0, WoT, 2048);
        convT_kernel<<<dim3(88, 32), 256, 0, stream>>>(Wg_l, 5632, 0, guT, 2048);
        convT_kernel<<<dim3(88, 32), 256, 0, stream>>>(Wu_l, 5632, 0, guT + 5632 * 2048, 2048);
        convT_kernel<<<dim3(32, 88), 256, 0, stream>>>(Wd_l, 2048, 0, WdT, 5632);

        // fused QKV projection: [1024,3072]
        bgemm_kernel<u16><<<dim3(8, 24, 1), 256, 0, stream>>>(
            h, 2048, 0, qkvT, 2048, 0, qkv, 3072, 0, 2048);
        rope_q_kernel<<<4096, 256, 0, stream>>>(qkv);
        build_k_kernel<<<dim3(768, 16), 256, 0, stream>>>(kc, qkv, kf);
        build_vT_kernel<<<dim3(48, 16), 256, 0, stream>>>(vc, qkv, vfT);

        // fused attention (scores+mask+softmax+PV)
        flash_kernel<<<dim3(32, 16), 128, 0, stream>>>(qkv, kf, vfT, attn);

        // Wo with split-K, partials then fused add+rmsnorm(ln2)
        bgemm_kernel<float><<<dim3(8, 16, 2), 256, 0, stream>>>(
            attn, 2048, 1024, WoT, 2048, 1024,
            partWo, 2048, (long)1024 * 2048, 1024);
        rmsadd2_kernel<<<1024, 256, 0, stream>>>(x, partWo, partWo + 2097152, ln2 + l * 2048, h);

        // fused gate+up: [1024,11264] on the pipelined 256x256 engine
        bgemm256_kernel<u16><<<dim3(4, 44), 512, 0, stream>>>(
            h, 2048, guT, 2048, gu, 11264, 2048);
        silu_mul_kernel<<<dim3(11, 1024), 256, 0, stream>>>((u32*)gu);

        // Wd with split-K, partials then fused add+rmsnorm(next norm weight)
        bgemm_kernel<float><<<dim3(8, 16, 2), 256, 0, stream>>>(
            gu, 11264, 2816, WdT, 5632, 2816,
            partWd, 2048, (long)1024 * 2048, 2816);
        rmsadd2_kernel<<<1024, 256, 0, stream>>>(
            x, partWd, partWd + 2097152, (l == 0) ? (ln1 + 2048) : normw, h);
    }

    // lm_head on the pipelined 256x256 engine (grid 4x125 = 500 blocks, m204 swizzle)
    convT_kernel<<<dim3(500, 32), 256, 0, stream>>>(lmh, 32000, 0, lmT, 2048);
    bgemm256_kernel<float><<<dim3(4, 125), 512, 0, stream>>>(
        h, 2048, lmT, 2048, out, 32000, 2048);
}